// Round 1
// baseline (2806.809 us; speedup 1.0000x reference)
//
#include <hip/hip_runtime.h>
#include <cmath>

#define B_ 4
#define S_ 2048
#define D_ 1024
#define H_ 16
#define HD_ 64

// ---------------- GEMM NT: C[M,N] = A[M,K] * B[N,K]^T + bias[N] ----------------
// A row-major (K contiguous), B row-major (K contiguous) -> both tiles load coalesced.
// 64x64 tile, 256 threads, 4x4 register blocking. LDS stride 17 -> worst 2-way bank
// aliasing (free on CDNA4 per m136).
__global__ __launch_bounds__(256)
void gemm_nt_kernel(const float* __restrict__ A, const float* __restrict__ Bm,
                    const float* __restrict__ bias, float* __restrict__ C,
                    int M, int N, int K)
{
    __shared__ float As[64][17];
    __shared__ float Bs[64][17];
    const int tid = threadIdx.x;
    const int bm = blockIdx.x * 64;
    const int bn = blockIdx.y * 64;
    const int lr = tid >> 2;          // 0..63 staging row
    const int lc = (tid & 3) * 4;     // 0,4,8,12 staging col (float4)
    const int tx = tid & 15;
    const int ty = tid >> 4;

    float acc[4][4] = {};
    const float* Arow = A + (size_t)(bm + lr) * K + lc;
    const float* Brow = Bm + (size_t)(bn + lr) * K + lc;

    for (int k0 = 0; k0 < K; k0 += 16) {
        float4 a4 = *reinterpret_cast<const float4*>(Arow + k0);
        float4 b4 = *reinterpret_cast<const float4*>(Brow + k0);
        __syncthreads();
        As[lr][lc+0] = a4.x; As[lr][lc+1] = a4.y; As[lr][lc+2] = a4.z; As[lr][lc+3] = a4.w;
        Bs[lr][lc+0] = b4.x; Bs[lr][lc+1] = b4.y; Bs[lr][lc+2] = b4.z; Bs[lr][lc+3] = b4.w;
        __syncthreads();
#pragma unroll
        for (int kk = 0; kk < 16; ++kk) {
            float av[4], bv[4];
#pragma unroll
            for (int i = 0; i < 4; ++i) av[i] = As[ty*4+i][kk];
#pragma unroll
            for (int j = 0; j < 4; ++j) bv[j] = Bs[tx*4+j][kk];
#pragma unroll
            for (int i = 0; i < 4; ++i)
#pragma unroll
                for (int j = 0; j < 4; ++j)
                    acc[i][j] = fmaf(av[i], bv[j], acc[i][j]);
        }
    }
#pragma unroll
    for (int i = 0; i < 4; ++i) {
        const int row = bm + ty*4 + i;
#pragma unroll
        for (int j = 0; j < 4; ++j) {
            const int col = bn + tx*4 + j;
            C[(size_t)row * N + col] = acc[i][j] + bias[col];
        }
    }
}

// ---------------- RoPE (in-place on q and k, layout (B,S,H,64)) ----------------
// Reference quirk: emb = concat([sin, cos]); c = emb[:,:32] = SIN, s = emb[:,32:] = COS.
// out1 = x1*sin - x2*cos ; out2 = x2*sin + x1*cos.
// t up to ~2047 rad -> must use libm sinf/cosf (range reduction), not __sinf.
__global__ __launch_bounds__(256)
void rope_kernel(float* __restrict__ q, float* __restrict__ k)
{
    const int bs = blockIdx.x;            // 0 .. B*S-1
    const int s = bs & (S_ - 1);
    const size_t base = (size_t)bs * D_;
    const int tid = threadIdx.x;
    // ln(10000)/32
    const float kfreq = 0.28782313662425572f;
    for (int p = tid; p < H_ * 32; p += 256) {
        const int h = p >> 5;
        const int i = p & 31;
        const float freq = expf(-(float)i * kfreq);
        const float t = (float)s * freq;
        const float sn = sinf(t);
        const float cs = cosf(t);
        const size_t i1 = base + (size_t)h * 64 + i;
        const size_t i2 = i1 + 32;
        const float q1 = q[i1], q2 = q[i2];
        q[i1] = q1 * sn - q2 * cs;
        q[i2] = q2 * sn + q1 * cs;
        const float k1 = k[i1], k2 = k[i2];
        k[i1] = k1 * sn - k2 * cs;
        k[i2] = k2 * sn + k1 * cs;
    }
}

// ---------------- Flash-style attention, fp32 ----------------
// One block per (b, h, 64-query tile). Online softmax. K-tile LDS buffer is
// reused to hold P between QK^T and PV. ctx may alias q (each block writes only
// the exact (rows, head-cols) region whose q it alone reads, after staging).
__global__ __launch_bounds__(256)
void attn_kernel(const float* __restrict__ q, const float* __restrict__ k,
                 const float* __restrict__ v, float* __restrict__ ctx)
{
    __shared__ float Qs[64][65];
    __shared__ float Ks[64][65];   // reused as P after scores
    __shared__ float Vs[64][65];

    const int blk = blockIdx.x;
    const int qt = blk & 31;
    const int h  = (blk >> 5) & 15;
    const int b  = blk >> 9;

    const int tid = threadIdx.x;
    const int tx = tid & 15;      // wave bits 0..3 -> shfl_xor {1,2,4,8} reduces over tx
    const int ty = tid >> 4;

    // stage Q tile (64 rows x 64 cols)
#pragma unroll
    for (int it = 0; it < 4; ++it) {
        const int idx = it * 256 + tid;      // 0..1023
        const int row = idx >> 4;
        const int c4 = (idx & 15) * 4;
        const float4 val = *reinterpret_cast<const float4*>(
            q + ((size_t)(b * S_ + qt * 64 + row) * D_ + h * 64 + c4));
        Qs[row][c4+0] = val.x; Qs[row][c4+1] = val.y;
        Qs[row][c4+2] = val.z; Qs[row][c4+3] = val.w;
    }

    float m_i[4], l_i[4], O[4][4];
#pragma unroll
    for (int i = 0; i < 4; ++i) {
        m_i[i] = -1e30f; l_i[i] = 0.f;
#pragma unroll
        for (int j = 0; j < 4; ++j) O[i][j] = 0.f;
    }

    for (int kt = 0; kt < 32; ++kt) {
        __syncthreads();   // prev PV / Q staging complete before restaging K,V
#pragma unroll
        for (int it = 0; it < 4; ++it) {
            const int idx = it * 256 + tid;
            const int row = idx >> 4;
            const int c4 = (idx & 15) * 4;
            const size_t off = (size_t)(b * S_ + kt * 64 + row) * D_ + h * 64 + c4;
            const float4 kv = *reinterpret_cast<const float4*>(k + off);
            Ks[row][c4+0] = kv.x; Ks[row][c4+1] = kv.y;
            Ks[row][c4+2] = kv.z; Ks[row][c4+3] = kv.w;
            const float4 vv = *reinterpret_cast<const float4*>(v + off);
            Vs[row][c4+0] = vv.x; Vs[row][c4+1] = vv.y;
            Vs[row][c4+2] = vv.z; Vs[row][c4+3] = vv.w;
        }
        __syncthreads();

        // S = Q K^T  (each thread: 4 rows x 4 cols)
        float s[4][4] = {};
#pragma unroll 8
        for (int kk = 0; kk < 64; ++kk) {
            float qv[4], kv[4];
#pragma unroll
            for (int i = 0; i < 4; ++i) qv[i] = Qs[ty*4+i][kk];
#pragma unroll
            for (int j = 0; j < 4; ++j) kv[j] = Ks[tx*4+j][kk];
#pragma unroll
            for (int i = 0; i < 4; ++i)
#pragma unroll
                for (int j = 0; j < 4; ++j)
                    s[i][j] = fmaf(qv[i], kv[j], s[i][j]);
        }

        // online softmax (per query row; replicated across the 16 tx lanes)
        const float scale = 0.125f;   // 1/sqrt(64)
        float p[4][4];
#pragma unroll
        for (int i = 0; i < 4; ++i) {
            float mx = -1e30f;
#pragma unroll
            for (int j = 0; j < 4; ++j) { s[i][j] *= scale; mx = fmaxf(mx, s[i][j]); }
#pragma unroll
            for (int d = 1; d < 16; d <<= 1) mx = fmaxf(mx, __shfl_xor(mx, d, 64));
            const float m_new = fmaxf(m_i[i], mx);
            const float alpha = __expf(m_i[i] - m_new);
            float sum = 0.f;
#pragma unroll
            for (int j = 0; j < 4; ++j) { p[i][j] = __expf(s[i][j] - m_new); sum += p[i][j]; }
#pragma unroll
            for (int d = 1; d < 16; d <<= 1) sum += __shfl_xor(sum, d, 64);
            l_i[i] = l_i[i] * alpha + sum;
            m_i[i] = m_new;
#pragma unroll
            for (int j = 0; j < 4; ++j) O[i][j] *= alpha;
        }

        __syncthreads();   // everyone done reading Ks as K
#pragma unroll
        for (int i = 0; i < 4; ++i)
#pragma unroll
            for (int j = 0; j < 4; ++j)
                Ks[ty*4+i][tx*4+j] = p[i][j];
        __syncthreads();

        // O += P V  (thread: 4 rows x 4 dims)
#pragma unroll 8
        for (int kk = 0; kk < 64; ++kk) {
            float pv[4], vv[4];
#pragma unroll
            for (int i = 0; i < 4; ++i) pv[i] = Ks[ty*4+i][kk];
#pragma unroll
            for (int j = 0; j < 4; ++j) vv[j] = Vs[kk][tx*4+j];
#pragma unroll
            for (int i = 0; i < 4; ++i)
#pragma unroll
                for (int j = 0; j < 4; ++j)
                    O[i][j] = fmaf(pv[i], vv[j], O[i][j]);
        }
    }

#pragma unroll
    for (int i = 0; i < 4; ++i) {
        const float inv = 1.0f / l_i[i];
        const int row = qt * 64 + ty * 4 + i;
        const size_t base = ((size_t)(b * S_) + row) * D_ + (size_t)h * 64;
#pragma unroll
        for (int j = 0; j < 4; ++j)
            ctx[base + tx * 4 + j] = O[i][j] * inv;
    }
}

extern "C" void kernel_launch(void* const* d_in, const int* in_sizes, int n_in,
                              void* d_out, int out_size, void* d_ws, size_t ws_size,
                              hipStream_t stream) {
    (void)in_sizes; (void)n_in; (void)out_size; (void)ws_size;
    const float* X  = (const float*)d_in[0];
    const float* Wq = (const float*)d_in[1];
    const float* bq = (const float*)d_in[2];
    const float* Wk = (const float*)d_in[3];
    const float* bk = (const float*)d_in[4];
    const float* Wv = (const float*)d_in[5];
    const float* bv = (const float*)d_in[6];
    const float* Wo = (const float*)d_in[7];
    const float* bo = (const float*)d_in[8];
    float* out = (float*)d_out;

    const size_t elems = (size_t)B_ * S_ * D_;   // 8M floats = 32 MB
    float* qb = (float*)d_ws;
    float* kb = qb + elems;
    float* vb = kb + elems;
    // ctx aliases qb (safe: see attn_kernel comment). Total ws use: 96 MB.

    dim3 gridG(128, 16), blockG(256);
    gemm_nt_kernel<<<gridG, blockG, 0, stream>>>(X, Wq, bq, qb, B_*S_, D_, D_);
    gemm_nt_kernel<<<gridG, blockG, 0, stream>>>(X, Wk, bk, kb, B_*S_, D_, D_);
    gemm_nt_kernel<<<gridG, blockG, 0, stream>>>(X, Wv, bv, vb, B_*S_, D_, D_);
    rope_kernel<<<B_*S_, 256, 0, stream>>>(qb, kb);
    attn_kernel<<<B_*H_*(S_/64), 256, 0, stream>>>(qb, kb, vb, qb);
    gemm_nt_kernel<<<gridG, blockG, 0, stream>>>(qb, Wo, bo, out, B_*S_, D_, D_);
}

// Round 2
// 1765.559 us; speedup vs baseline: 1.5898x; 1.5898x over previous
//
#include <hip/hip_runtime.h>
#include <cmath>

#define B_ 4
#define S_ 2048
#define D_ 1024
#define H_ 16
#define HD_ 64

typedef __attribute__((ext_vector_type(8))) short short8;
typedef __attribute__((ext_vector_type(4))) float floatx4;

// ---------------- split-bf16 helpers ----------------
__device__ __forceinline__ unsigned short bf_rne(float x) {
    unsigned u = __float_as_uint(x);
    u += 0x7fffu + ((u >> 16) & 1u);
    return (unsigned short)(u >> 16);
}
__device__ __forceinline__ float bf_to_f(unsigned short h) {
    return __uint_as_float(((unsigned)h) << 16);
}
// 8 fp32 -> 8 bf16 hi + 8 bf16 lo (lo = rne(x - hi)), packed 16B each.
__device__ __forceinline__ void split_pack8(const float4 a, const float4 b,
                                            uint4& hi, uint4& lo) {
    float xs[8] = {a.x, a.y, a.z, a.w, b.x, b.y, b.z, b.w};
    unsigned h[8], lw[8];
#pragma unroll
    for (int t = 0; t < 8; ++t) {
        unsigned short hh = bf_rne(xs[t]);
        h[t] = hh;
        float r = xs[t] - bf_to_f(hh);   // exact in fp32
        lw[t] = bf_rne(r);
    }
    hi = make_uint4(h[0] | (h[1] << 16), h[2] | (h[3] << 16),
                    h[4] | (h[5] << 16), h[6] | (h[7] << 16));
    lo = make_uint4(lw[0] | (lw[1] << 16), lw[2] | (lw[3] << 16),
                    lw[4] | (lw[5] << 16), lw[6] | (lw[7] << 16));
}

// ---------------- GEMM NT via split-bf16 MFMA ----------------
// C[M,N] = A[M,K] * W[N,K]^T + bias[N].  fp32 in/out; internally x = hi+lo bf16,
// acc += hi*hi + hi*lo + lo*hi (3 MFMAs) -> ~fp32 accuracy at MFMA rate.
// Block: 128x128 tile, BK=32, 256 thr = 4 waves (2x2 of 64x64 per wave,
// each wave 4x4 tiles of 16x16x32 MFMA).
// LDS fragment order: per 16-row mtile, frag l <-> (row=l&15, quad=l>>4),
// content = X[mtile*16+row][k0 + quad*8 .. +7]; lane l reads offset l*16B ->
// conflict-free ds_read_b128, and matches the MFMA A/B operand layout
// (A[m=lane&15][k=quad*8+j], B^T[n=lane&15][k=quad*8+j]).
__global__ __launch_bounds__(256, 2)
void gemm_mfma_split(const float* __restrict__ A, const float* __restrict__ W,
                     const float* __restrict__ bias, float* __restrict__ C,
                     int M, int N, int K)
{
    __shared__ uint4 Ah[512];   // 8 mtiles x 64 frags
    __shared__ uint4 Al[512];
    __shared__ uint4 Bh[512];
    __shared__ uint4 Bl[512];

    const int tid = threadIdx.x;
    const int bm = blockIdx.x * 128;
    const int bn = blockIdx.y * 128;
    const int w  = tid >> 6;
    const int l  = tid & 63;
    const int wm = (w & 1) * 64;
    const int wn = (w >> 1) * 64;

    floatx4 acc[4][4];
#pragma unroll
    for (int i = 0; i < 4; ++i)
#pragma unroll
        for (int j = 0; j < 4; ++j)
#pragma unroll
            for (int r = 0; r < 4; ++r) acc[i][j][r] = 0.f;

    // staging: frag p in [0,512): row = p>>2, quad = p&3. Thread t -> p=t, p=t+256.
    const int r0 = tid >> 2, q0 = tid & 3;
    const float* gA0 = A + (size_t)(bm + r0) * K + q0 * 8;
    const float* gA1 = A + (size_t)(bm + r0 + 64) * K + q0 * 8;
    const float* gB0 = W + (size_t)(bn + r0) * K + q0 * 8;
    const float* gB1 = W + (size_t)(bn + r0 + 64) * K + q0 * 8;
    const int f0 = ((r0 >> 4) << 6) | (q0 << 4) | (r0 & 15);
    const int f1 = f0 + 256;   // rows +64 -> mtile +4 -> +4*64 frags

    const short8* pAh = (const short8*)Ah;
    const short8* pAl = (const short8*)Al;
    const short8* pBh = (const short8*)Bh;
    const short8* pBl = (const short8*)Bl;
    const int am = (wm >> 4) * 64 + l;   // frag index base for this wave's a-tiles
    const int bnf = (wn >> 4) * 64 + l;

    for (int k0 = 0; k0 < K; k0 += 32) {
        const float4 a00 = *reinterpret_cast<const float4*>(gA0 + k0);
        const float4 a01 = *reinterpret_cast<const float4*>(gA0 + k0 + 4);
        const float4 a10 = *reinterpret_cast<const float4*>(gA1 + k0);
        const float4 a11 = *reinterpret_cast<const float4*>(gA1 + k0 + 4);
        const float4 b00 = *reinterpret_cast<const float4*>(gB0 + k0);
        const float4 b01 = *reinterpret_cast<const float4*>(gB0 + k0 + 4);
        const float4 b10 = *reinterpret_cast<const float4*>(gB1 + k0);
        const float4 b11 = *reinterpret_cast<const float4*>(gB1 + k0 + 4);

        __syncthreads();   // prev iter's LDS consumers done
        {
            uint4 hi, lo;
            split_pack8(a00, a01, hi, lo); Ah[f0] = hi; Al[f0] = lo;
            split_pack8(a10, a11, hi, lo); Ah[f1] = hi; Al[f1] = lo;
            split_pack8(b00, b01, hi, lo); Bh[f0] = hi; Bl[f0] = lo;
            split_pack8(b10, b11, hi, lo); Bh[f1] = hi; Bl[f1] = lo;
        }
        __syncthreads();

        short8 ah[4], al[4];
#pragma unroll
        for (int i = 0; i < 4; ++i) {
            ah[i] = pAh[am + i * 64];
            al[i] = pAl[am + i * 64];
        }
#pragma unroll
        for (int j = 0; j < 4; ++j) {
            const short8 bh = pBh[bnf + j * 64];
            const short8 bl = pBl[bnf + j * 64];
#pragma unroll
            for (int i = 0; i < 4; ++i) {
                acc[i][j] = __builtin_amdgcn_mfma_f32_16x16x32_bf16(ah[i], bh, acc[i][j], 0, 0, 0);
                acc[i][j] = __builtin_amdgcn_mfma_f32_16x16x32_bf16(ah[i], bl, acc[i][j], 0, 0, 0);
                acc[i][j] = __builtin_amdgcn_mfma_f32_16x16x32_bf16(al[i], bh, acc[i][j], 0, 0, 0);
            }
        }
    }

    // epilogue: C/D layout col=lane&15, row=(lane>>4)*4+reg
    const int cr = (l >> 4) << 2;
    const int cc = l & 15;
#pragma unroll
    for (int j = 0; j < 4; ++j) {
        const int col = bn + wn + j * 16 + cc;
        const float bv = bias[col];
#pragma unroll
        for (int i = 0; i < 4; ++i) {
            const int row = bm + wm + i * 16 + cr;
#pragma unroll
            for (int r = 0; r < 4; ++r)
                C[(size_t)(row + r) * N + col] = acc[i][j][r] + bv;
        }
    }
}

// ---------------- RoPE (in-place on q and k, layout (B,S,H,64)) ----------------
// Reference quirk: emb = concat([sin, cos]); c = emb[:,:32] = SIN, s = emb[:,32:] = COS.
// out1 = x1*sin - x2*cos ; out2 = x2*sin + x1*cos.  libm sinf/cosf (t up to ~2047 rad).
__global__ __launch_bounds__(256)
void rope_kernel(float* __restrict__ q, float* __restrict__ k)
{
    const int bs = blockIdx.x;
    const int s = bs & (S_ - 1);
    const size_t base = (size_t)bs * D_;
    const int tid = threadIdx.x;
    const float kfreq = 0.28782313662425572f;   // ln(10000)/32
    for (int p = tid; p < H_ * 32; p += 256) {
        const int h = p >> 5;
        const int i = p & 31;
        const float freq = expf(-(float)i * kfreq);
        const float t = (float)s * freq;
        const float sn = sinf(t);
        const float cs = cosf(t);
        const size_t i1 = base + (size_t)h * 64 + i;
        const size_t i2 = i1 + 32;
        const float q1 = q[i1], q2 = q[i2];
        q[i1] = q1 * sn - q2 * cs;
        q[i2] = q2 * sn + q1 * cs;
        const float k1 = k[i1], k2 = k[i2];
        k[i1] = k1 * sn - k2 * cs;
        k[i2] = k2 * sn + k1 * cs;
    }
}

// ---------------- Flash-style attention, fp32 (unchanged this round) ----------------
__global__ __launch_bounds__(256)
void attn_kernel(const float* __restrict__ q, const float* __restrict__ k,
                 const float* __restrict__ v, float* __restrict__ ctx)
{
    __shared__ float Qs[64][65];
    __shared__ float Ks[64][65];   // reused as P after scores
    __shared__ float Vs[64][65];

    const int blk = blockIdx.x;
    const int qt = blk & 31;
    const int h  = (blk >> 5) & 15;
    const int b  = blk >> 9;

    const int tid = threadIdx.x;
    const int tx = tid & 15;
    const int ty = tid >> 4;

#pragma unroll
    for (int it = 0; it < 4; ++it) {
        const int idx = it * 256 + tid;
        const int row = idx >> 4;
        const int c4 = (idx & 15) * 4;
        const float4 val = *reinterpret_cast<const float4*>(
            q + ((size_t)(b * S_ + qt * 64 + row) * D_ + h * 64 + c4));
        Qs[row][c4+0] = val.x; Qs[row][c4+1] = val.y;
        Qs[row][c4+2] = val.z; Qs[row][c4+3] = val.w;
    }

    float m_i[4], l_i[4], O[4][4];
#pragma unroll
    for (int i = 0; i < 4; ++i) {
        m_i[i] = -1e30f; l_i[i] = 0.f;
#pragma unroll
        for (int j = 0; j < 4; ++j) O[i][j] = 0.f;
    }

    for (int kt = 0; kt < 32; ++kt) {
        __syncthreads();
#pragma unroll
        for (int it = 0; it < 4; ++it) {
            const int idx = it * 256 + tid;
            const int row = idx >> 4;
            const int c4 = (idx & 15) * 4;
            const size_t off = (size_t)(b * S_ + kt * 64 + row) * D_ + h * 64 + c4;
            const float4 kv = *reinterpret_cast<const float4*>(k + off);
            Ks[row][c4+0] = kv.x; Ks[row][c4+1] = kv.y;
            Ks[row][c4+2] = kv.z; Ks[row][c4+3] = kv.w;
            const float4 vv = *reinterpret_cast<const float4*>(v + off);
            Vs[row][c4+0] = vv.x; Vs[row][c4+1] = vv.y;
            Vs[row][c4+2] = vv.z; Vs[row][c4+3] = vv.w;
        }
        __syncthreads();

        float s[4][4] = {};
#pragma unroll 8
        for (int kk = 0; kk < 64; ++kk) {
            float qv[4], kv[4];
#pragma unroll
            for (int i = 0; i < 4; ++i) qv[i] = Qs[ty*4+i][kk];
#pragma unroll
            for (int j = 0; j < 4; ++j) kv[j] = Ks[tx*4+j][kk];
#pragma unroll
            for (int i = 0; i < 4; ++i)
#pragma unroll
                for (int j = 0; j < 4; ++j)
                    s[i][j] = fmaf(qv[i], kv[j], s[i][j]);
        }

        const float scale = 0.125f;
        float p[4][4];
#pragma unroll
        for (int i = 0; i < 4; ++i) {
            float mx = -1e30f;
#pragma unroll
            for (int j = 0; j < 4; ++j) { s[i][j] *= scale; mx = fmaxf(mx, s[i][j]); }
#pragma unroll
            for (int d = 1; d < 16; d <<= 1) mx = fmaxf(mx, __shfl_xor(mx, d, 64));
            const float m_new = fmaxf(m_i[i], mx);
            const float alpha = __expf(m_i[i] - m_new);
            float sum = 0.f;
#pragma unroll
            for (int j = 0; j < 4; ++j) { p[i][j] = __expf(s[i][j] - m_new); sum += p[i][j]; }
#pragma unroll
            for (int d = 1; d < 16; d <<= 1) sum += __shfl_xor(sum, d, 64);
            l_i[i] = l_i[i] * alpha + sum;
            m_i[i] = m_new;
#pragma unroll
            for (int j = 0; j < 4; ++j) O[i][j] *= alpha;
        }

        __syncthreads();
#pragma unroll
        for (int i = 0; i < 4; ++i)
#pragma unroll
            for (int j = 0; j < 4; ++j)
                Ks[ty*4+i][tx*4+j] = p[i][j];
        __syncthreads();

#pragma unroll 8
        for (int kk = 0; kk < 64; ++kk) {
            float pv[4], vv[4];
#pragma unroll
            for (int i = 0; i < 4; ++i) pv[i] = Ks[ty*4+i][kk];
#pragma unroll
            for (int j = 0; j < 4; ++j) vv[j] = Vs[kk][tx*4+j];
#pragma unroll
            for (int i = 0; i < 4; ++i)
#pragma unroll
                for (int j = 0; j < 4; ++j)
                    O[i][j] = fmaf(pv[i], vv[j], O[i][j]);
        }
    }

#pragma unroll
    for (int i = 0; i < 4; ++i) {
        const float inv = 1.0f / l_i[i];
        const int row = qt * 64 + ty * 4 + i;
        const size_t base = ((size_t)(b * S_) + row) * D_ + (size_t)h * 64;
#pragma unroll
        for (int j = 0; j < 4; ++j)
            ctx[base + tx * 4 + j] = O[i][j] * inv;
    }
}

extern "C" void kernel_launch(void* const* d_in, const int* in_sizes, int n_in,
                              void* d_out, int out_size, void* d_ws, size_t ws_size,
                              hipStream_t stream) {
    (void)in_sizes; (void)n_in; (void)out_size; (void)ws_size;
    const float* X  = (const float*)d_in[0];
    const float* Wq = (const float*)d_in[1];
    const float* bq = (const float*)d_in[2];
    const float* Wk = (const float*)d_in[3];
    const float* bk = (const float*)d_in[4];
    const float* Wv = (const float*)d_in[5];
    const float* bv = (const float*)d_in[6];
    const float* Wo = (const float*)d_in[7];
    const float* bo = (const float*)d_in[8];
    float* out = (float*)d_out;

    const size_t elems = (size_t)B_ * S_ * D_;   // 8M floats = 32 MB
    float* qb = (float*)d_ws;
    float* kb = qb + elems;
    float* vb = kb + elems;

    dim3 gridG(64, 8), blockG(256);   // 8192/128 x 1024/128
    gemm_mfma_split<<<gridG, blockG, 0, stream>>>(X, Wq, bq, qb, B_*S_, D_, D_);
    gemm_mfma_split<<<gridG, blockG, 0, stream>>>(X, Wk, bk, kb, B_*S_, D_, D_);
    gemm_mfma_split<<<gridG, blockG, 0, stream>>>(X, Wv, bv, vb, B_*S_, D_, D_);
    rope_kernel<<<B_*S_, 256, 0, stream>>>(qb, kb);
    attn_kernel<<<B_*H_*(S_/64), 256, 0, stream>>>(qb, kb, vb, qb);
    gemm_mfma_split<<<gridG, blockG, 0, stream>>>(qb, Wo, bo, out, B_*S_, D_, D_);
}

// Round 4
// 591.638 us; speedup vs baseline: 4.7441x; 2.9842x over previous
//
#include <hip/hip_runtime.h>
#include <cmath>

#define B_ 4
#define S_ 2048
#define D_ 1024
#define H_ 16
#define HD_ 64

typedef __attribute__((ext_vector_type(8))) short short8;
typedef __attribute__((ext_vector_type(4))) float floatx4;

// ---------------- bf16 helpers ----------------
__device__ __forceinline__ unsigned short bf_rne(float x) {
    unsigned u = __float_as_uint(x);
    u += 0x7fffu + ((u >> 16) & 1u);
    return (unsigned short)(u >> 16);
}
__device__ __forceinline__ float bf_to_f(unsigned short h) {
    return __uint_as_float(((unsigned)h) << 16);
}
__device__ __forceinline__ unsigned bfpack2(float a, float b) {
    return (unsigned)bf_rne(a) | ((unsigned)bf_rne(b) << 16);
}
__device__ __forceinline__ void split_pack8(const float4 a, const float4 b,
                                            uint4& hi, uint4& lo) {
    float xs[8] = {a.x, a.y, a.z, a.w, b.x, b.y, b.z, b.w};
    unsigned h[8], lw[8];
#pragma unroll
    for (int t = 0; t < 8; ++t) {
        unsigned short hh = bf_rne(xs[t]);
        h[t] = hh;
        float r = xs[t] - bf_to_f(hh);
        lw[t] = bf_rne(r);
    }
    hi = make_uint4(h[0] | (h[1] << 16), h[2] | (h[3] << 16),
                    h[4] | (h[5] << 16), h[6] | (h[7] << 16));
    lo = make_uint4(lw[0] | (lw[1] << 16), lw[2] | (lw[3] << 16),
                    lw[4] | (lw[5] << 16), lw[6] | (lw[7] << 16));
}

// ---------------- GEMM NT via split-bf16 MFMA (unchanged from R2) ----------------
__global__ __launch_bounds__(256, 2)
void gemm_mfma_split(const float* __restrict__ A, const float* __restrict__ W,
                     const float* __restrict__ bias, float* __restrict__ C,
                     int M, int N, int K)
{
    __shared__ uint4 Ah[512];
    __shared__ uint4 Al[512];
    __shared__ uint4 Bh[512];
    __shared__ uint4 Bl[512];

    const int tid = threadIdx.x;
    const int bm = blockIdx.x * 128;
    const int bn = blockIdx.y * 128;
    const int w  = tid >> 6;
    const int l  = tid & 63;
    const int wm = (w & 1) * 64;
    const int wn = (w >> 1) * 64;

    floatx4 acc[4][4];
#pragma unroll
    for (int i = 0; i < 4; ++i)
#pragma unroll
        for (int j = 0; j < 4; ++j)
#pragma unroll
            for (int r = 0; r < 4; ++r) acc[i][j][r] = 0.f;

    const int r0 = tid >> 2, q0 = tid & 3;
    const float* gA0 = A + (size_t)(bm + r0) * K + q0 * 8;
    const float* gA1 = A + (size_t)(bm + r0 + 64) * K + q0 * 8;
    const float* gB0 = W + (size_t)(bn + r0) * K + q0 * 8;
    const float* gB1 = W + (size_t)(bn + r0 + 64) * K + q0 * 8;
    const int f0 = ((r0 >> 4) << 6) | (q0 << 4) | (r0 & 15);
    const int f1 = f0 + 256;

    const short8* pAh = (const short8*)Ah;
    const short8* pAl = (const short8*)Al;
    const short8* pBh = (const short8*)Bh;
    const short8* pBl = (const short8*)Bl;
    const int am = (wm >> 4) * 64 + l;
    const int bnf = (wn >> 4) * 64 + l;

    for (int k0 = 0; k0 < K; k0 += 32) {
        const float4 a00 = *reinterpret_cast<const float4*>(gA0 + k0);
        const float4 a01 = *reinterpret_cast<const float4*>(gA0 + k0 + 4);
        const float4 a10 = *reinterpret_cast<const float4*>(gA1 + k0);
        const float4 a11 = *reinterpret_cast<const float4*>(gA1 + k0 + 4);
        const float4 b00 = *reinterpret_cast<const float4*>(gB0 + k0);
        const float4 b01 = *reinterpret_cast<const float4*>(gB0 + k0 + 4);
        const float4 b10 = *reinterpret_cast<const float4*>(gB1 + k0);
        const float4 b11 = *reinterpret_cast<const float4*>(gB1 + k0 + 4);

        __syncthreads();
        {
            uint4 hi, lo;
            split_pack8(a00, a01, hi, lo); Ah[f0] = hi; Al[f0] = lo;
            split_pack8(a10, a11, hi, lo); Ah[f1] = hi; Al[f1] = lo;
            split_pack8(b00, b01, hi, lo); Bh[f0] = hi; Bl[f0] = lo;
            split_pack8(b10, b11, hi, lo); Bh[f1] = hi; Bl[f1] = lo;
        }
        __syncthreads();

        short8 ah[4], al[4];
#pragma unroll
        for (int i = 0; i < 4; ++i) {
            ah[i] = pAh[am + i * 64];
            al[i] = pAl[am + i * 64];
        }
#pragma unroll
        for (int j = 0; j < 4; ++j) {
            const short8 bh = pBh[bnf + j * 64];
            const short8 bl = pBl[bnf + j * 64];
#pragma unroll
            for (int i = 0; i < 4; ++i) {
                acc[i][j] = __builtin_amdgcn_mfma_f32_16x16x32_bf16(ah[i], bh, acc[i][j], 0, 0, 0);
                acc[i][j] = __builtin_amdgcn_mfma_f32_16x16x32_bf16(ah[i], bl, acc[i][j], 0, 0, 0);
                acc[i][j] = __builtin_amdgcn_mfma_f32_16x16x32_bf16(al[i], bh, acc[i][j], 0, 0, 0);
            }
        }
    }

    const int cr = (l >> 4) << 2;
    const int cc = l & 15;
#pragma unroll
    for (int j = 0; j < 4; ++j) {
        const int col = bn + wn + j * 16 + cc;
        const float bv = bias[col];
#pragma unroll
        for (int i = 0; i < 4; ++i) {
            const int row = bm + wm + i * 16 + cr;
#pragma unroll
            for (int r = 0; r < 4; ++r)
                C[(size_t)(row + r) * N + col] = acc[i][j][r] + bv;
        }
    }
}

// ---------------- prep: RoPE + bf16 convert for Q and K ----------------
// Reads q,k fp32 (B,S,D); writes Qb,Kb bf16 (B,S,D). K scaled by 0.125 (exact).
// Reference RoPE: c=sin, s=cos -> out1 = x1*sin - x2*cos; out2 = x2*sin + x1*cos.
__global__ __launch_bounds__(256)
void prep_qk_kernel(const float* __restrict__ q, const float* __restrict__ k,
                    unsigned short* __restrict__ Qb, unsigned short* __restrict__ Kb)
{
    const int bs = blockIdx.x;
    const int s = bs & (S_ - 1);
    const size_t base = (size_t)bs * D_;
    const int t = threadIdx.x;
    const int h = t >> 4;
    const int i2 = (t & 15) * 2;       // pair indices i2, i2+1
    const float kfreq = 0.28782313662425572f;  // ln(10000)/32

    const float f0 = expf(-(float)i2 * kfreq);
    const float f1 = expf(-(float)(i2 + 1) * kfreq);
    const float t0 = (float)s * f0, t1 = (float)s * f1;
    const float sn0 = sinf(t0), cs0 = cosf(t0);
    const float sn1 = sinf(t1), cs1 = cosf(t1);

    const size_t p1 = base + (size_t)h * 64 + i2;   // x1 pair
    const size_t p2 = p1 + 32;                      // x2 pair

    const float2 q1 = *(const float2*)(q + p1);
    const float2 q2 = *(const float2*)(q + p2);
    const float2 k1 = *(const float2*)(k + p1);
    const float2 k2 = *(const float2*)(k + p2);

    *(unsigned*)(Qb + p1) = bfpack2(q1.x * sn0 - q2.x * cs0, q1.y * sn1 - q2.y * cs1);
    *(unsigned*)(Qb + p2) = bfpack2(q2.x * sn0 + q1.x * cs0, q2.y * sn1 + q1.y * cs1);
    *(unsigned*)(Kb + p1) = bfpack2((k1.x * sn0 - k2.x * cs0) * 0.125f,
                                    (k1.y * sn1 - k2.y * cs1) * 0.125f);
    *(unsigned*)(Kb + p2) = bfpack2((k2.x * sn0 + k1.x * cs0) * 0.125f,
                                    (k2.y * sn1 + k1.y * cs1) * 0.125f);
}

// ---------------- V transpose+convert: fp32 (B,S,H*64) -> bf16 Vt (B,H,64,S) ----
__global__ __launch_bounds__(256)
void v_conv_kernel(const float* __restrict__ v, unsigned short* __restrict__ Vt)
{
    __shared__ float T[64][66];
    const int bx = blockIdx.x;             // (b,h,stile)
    const int st = bx & 31;                // S_/64
    const int h  = (bx >> 5) & 15;
    const int b  = bx >> 9;
    const int t = threadIdx.x;
    const int s0 = st * 64;

#pragma unroll
    for (int it = 0; it < 4; ++it) {
        const int idx = it * 256 + t;
        const int row = idx >> 4;
        const int c4 = (idx & 15) * 4;
        const float4 val = *(const float4*)(v + ((size_t)(b * S_ + s0 + row)) * D_ + h * 64 + c4);
        T[row][c4+0] = val.x; T[row][c4+1] = val.y;
        T[row][c4+2] = val.z; T[row][c4+3] = val.w;
    }
    __syncthreads();

    const int d = t >> 2;
    const int sc = (t & 3) * 16;
    unsigned u[8];
#pragma unroll
    for (int ii = 0; ii < 8; ++ii)
        u[ii] = bfpack2(T[sc + 2*ii][d], T[sc + 2*ii + 1][d]);
    unsigned short* dst = Vt + ((size_t)((b * H_ + h) * 64 + d)) * S_ + s0 + sc;
    *(uint4*)(dst)     = make_uint4(u[0], u[1], u[2], u[3]);
    *(uint4*)(dst + 8) = make_uint4(u[4], u[5], u[6], u[7]);
}

// ---------------- MFMA flash attention ----------------
// Computes S^T = K*Q^T per tile (C-layout col = query!), online softmax with
// per-lane-scalar m/l, P^T built in registers via shfl, PV as (PV)^T = V^T * P^T
// using pre-transposed Vt. Block = 128 q-rows (4 waves x 32), K-tile = 64.
__global__ __launch_bounds__(256)
void attn_mfma(const unsigned short* __restrict__ Qb,
               const unsigned short* __restrict__ Kb,
               const unsigned short* __restrict__ Vt,
               float* __restrict__ ctx)
{
    __shared__ uint4 Kf[512];   // 8 KB, B-frag order
    __shared__ uint4 Vf[512];   // 8 KB

    const int t = threadIdx.x;
    const int bx = blockIdx.x;
    const int qblk = bx & 15;             // S_/128
    const int h = (bx >> 4) & 15;
    const int b = bx >> 8;
    const int w = t >> 6, l = t & 63;
    const int lq = l & 15, quad = l >> 4;
    const int qrow0 = qblk * 128 + w * 32;

    // Q B-frags (held in registers for whole kernel): qt in {0,1}, c in {0,1}
    short8 qf[2][2];
#pragma unroll
    for (int qt = 0; qt < 2; ++qt)
#pragma unroll
        for (int c = 0; c < 2; ++c)
            qf[qt][c] = *(const short8*)(Qb + ((size_t)(b * S_ + qrow0 + qt * 16 + lq)) * D_
                                            + h * 64 + c * 32 + quad * 8);

    floatx4 O[2][4];
#pragma unroll
    for (int qt = 0; qt < 2; ++qt)
#pragma unroll
        for (int dt = 0; dt < 4; ++dt)
#pragma unroll
            for (int r = 0; r < 4; ++r) O[qt][dt][r] = 0.f;
    float m_i[2] = {-1e30f, -1e30f};
    float l_i[2] = {0.f, 0.f};

    // staging: thread t handles row sr, 16B chunks sq0 (c=0) and sq0+4 (c=1)
    const int sr = t >> 2, sq0 = t & 3;
    const int fi0 = (sr >> 4) * 128 + sq0 * 16 + (sr & 15);
    const unsigned short* Krow = Kb + ((size_t)(b * S_ + sr)) * D_ + h * 64;
    const unsigned short* Vrow = Vt + ((size_t)((b * H_ + h) * 64 + sr)) * S_;

    const short8* pK = (const short8*)Kf;
    const short8* pV = (const short8*)Vf;

    for (int kt = 0; kt < 32; ++kt) {
        const unsigned short* kr = Krow + (size_t)kt * 64 * D_;
        const unsigned short* vr = Vrow + kt * 64;
        const uint4 ka = *(const uint4*)(kr + sq0 * 8);
        const uint4 kb2 = *(const uint4*)(kr + sq0 * 8 + 32);
        const uint4 va = *(const uint4*)(vr + sq0 * 8);
        const uint4 vb2 = *(const uint4*)(vr + sq0 * 8 + 32);
        __syncthreads();
        Kf[fi0] = ka; Kf[fi0 + 64] = kb2;
        Vf[fi0] = va; Vf[fi0 + 64] = vb2;
        __syncthreads();

        // S^T tiles: st[qt][n], rows = key (within tile: quad*4+r), col = query (lq)
        floatx4 st[2][4];
#pragma unroll
        for (int qt = 0; qt < 2; ++qt)
#pragma unroll
            for (int n = 0; n < 4; ++n)
#pragma unroll
                for (int r = 0; r < 4; ++r) st[qt][n][r] = 0.f;
#pragma unroll
        for (int n = 0; n < 4; ++n) {
            const short8 k0 = pK[(n * 2 + 0) * 64 + l];
            const short8 k1 = pK[(n * 2 + 1) * 64 + l];
            st[0][n] = __builtin_amdgcn_mfma_f32_16x16x32_bf16(k0, qf[0][0], st[0][n], 0, 0, 0);
            st[0][n] = __builtin_amdgcn_mfma_f32_16x16x32_bf16(k1, qf[0][1], st[0][n], 0, 0, 0);
            st[1][n] = __builtin_amdgcn_mfma_f32_16x16x32_bf16(k0, qf[1][0], st[1][n], 0, 0, 0);
            st[1][n] = __builtin_amdgcn_mfma_f32_16x16x32_bf16(k1, qf[1][1], st[1][n], 0, 0, 0);
        }

        // V^T A-frags for this k-tile
        short8 vf[4][2];
#pragma unroll
        for (int dt = 0; dt < 4; ++dt)
#pragma unroll
            for (int c = 0; c < 2; ++c)
                vf[dt][c] = pV[(dt * 2 + c) * 64 + l];

#pragma unroll
        for (int qt = 0; qt < 2; ++qt) {
            float mx = st[qt][0][0];
#pragma unroll
            for (int n = 0; n < 4; ++n)
#pragma unroll
                for (int r = 0; r < 4; ++r) mx = fmaxf(mx, st[qt][n][r]);
            mx = fmaxf(mx, __shfl_xor(mx, 16, 64));
            mx = fmaxf(mx, __shfl_xor(mx, 32, 64));
            const float mn = fmaxf(m_i[qt], mx);
            const float alpha = __expf(m_i[qt] - mn);
            m_i[qt] = mn;

            float p[4][4];
            float sum = 0.f;
#pragma unroll
            for (int n = 0; n < 4; ++n)
#pragma unroll
                for (int r = 0; r < 4; ++r) {
                    p[n][r] = __expf(st[qt][n][r] - mn);
                    sum += p[n][r];
                }
            sum += __shfl_xor(sum, 16, 64);
            sum += __shfl_xor(sum, 32, 64);
            l_i[qt] = l_i[qt] * alpha + sum;
#pragma unroll
            for (int dt = 0; dt < 4; ++dt)
#pragma unroll
                for (int r = 0; r < 4; ++r) O[qt][dt][r] *= alpha;

            unsigned pp[4][2];
#pragma unroll
            for (int n = 0; n < 4; ++n) {
                pp[n][0] = bfpack2(p[n][0], p[n][1]);
                pp[n][1] = bfpack2(p[n][2], p[n][3]);
            }

            // Build P^T B-frags via shfl and do PV MFMAs.
#pragma unroll
            for (int c = 0; c < 2; ++c) {
                unsigned bb[4];
#pragma unroll
                for (int jp = 0; jp < 4; ++jp) {
                    const int src = (2 * (quad & 1) + (jp >> 1)) * 16 + lq;
                    const unsigned x0 = (unsigned)__shfl((int)pp[2 * c][jp & 1], src, 64);
                    const unsigned x1 = (unsigned)__shfl((int)pp[2 * c + 1][jp & 1], src, 64);
                    bb[jp] = (quad >> 1) ? x1 : x0;
                }
                union { unsigned u[4]; short8 s8; } pf;
                pf.u[0] = bb[0]; pf.u[1] = bb[1]; pf.u[2] = bb[2]; pf.u[3] = bb[3];
#pragma unroll
                for (int dt = 0; dt < 4; ++dt)
                    O[qt][dt] = __builtin_amdgcn_mfma_f32_16x16x32_bf16(vf[dt][c], pf.s8, O[qt][dt], 0, 0, 0);
            }
        }
    }

    // write ctx: O is (PV)^T -> lane col lq = query, rows = head-dim
#pragma unroll
    for (int qt = 0; qt < 2; ++qt) {
        const float inv = 1.0f / l_i[qt];
        float* crow = ctx + ((size_t)(b * S_ + qrow0 + qt * 16 + lq)) * D_ + h * 64;
#pragma unroll
        for (int dt = 0; dt < 4; ++dt) {
            float4 o;
            o.x = O[qt][dt][0] * inv; o.y = O[qt][dt][1] * inv;
            o.z = O[qt][dt][2] * inv; o.w = O[qt][dt][3] * inv;
            *(float4*)(crow + dt * 16 + quad * 4) = o;
        }
    }
}

extern "C" void kernel_launch(void* const* d_in, const int* in_sizes, int n_in,
                              void* d_out, int out_size, void* d_ws, size_t ws_size,
                              hipStream_t stream) {
    (void)in_sizes; (void)n_in; (void)out_size; (void)ws_size;
    const float* X  = (const float*)d_in[0];
    const float* Wq = (const float*)d_in[1];
    const float* bq = (const float*)d_in[2];
    const float* Wk = (const float*)d_in[3];
    const float* bk = (const float*)d_in[4];
    const float* Wv = (const float*)d_in[5];
    const float* bv = (const float*)d_in[6];
    const float* Wo = (const float*)d_in[7];
    const float* bo = (const float*)d_in[8];
    float* out = (float*)d_out;

    char* ws = (char*)d_ws;
    float* qb = (float*)(ws);                            // 32 MB
    float* kb = (float*)(ws + ((size_t)32 << 20));       // 32 MB
    float* vb = (float*)(ws + ((size_t)64 << 20));       // 32 MB
    unsigned short* Qbf = (unsigned short*)(ws + ((size_t)96 << 20));   // 16 MB
    unsigned short* Kbf = (unsigned short*)(ws + ((size_t)112 << 20));  // 16 MB
    unsigned short* Vtb = (unsigned short*)(ws + ((size_t)128 << 20));  // 16 MB

    dim3 gridG(64, 8), blockG(256);
    gemm_mfma_split<<<gridG, blockG, 0, stream>>>(X, Wq, bq, qb, B_*S_, D_, D_);
    gemm_mfma_split<<<gridG, blockG, 0, stream>>>(X, Wk, bk, kb, B_*S_, D_, D_);
    gemm_mfma_split<<<gridG, blockG, 0, stream>>>(X, Wv, bv, vb, B_*S_, D_, D_);
    prep_qk_kernel<<<B_*S_, 256, 0, stream>>>(qb, kb, Qbf, Kbf);
    v_conv_kernel<<<B_*H_*(S_/64), 256, 0, stream>>>(vb, Vtb);
    attn_mfma<<<B_*H_*(S_/128), 256, 0, stream>>>(Qbf, Kbf, Vtb, qb);  // ctx -> qb
    gemm_mfma_split<<<gridG, blockG, 0, stream>>>(qb, Wo, bo, out, B_*S_, D_, D_);
}

// Round 5
// 523.592 us; speedup vs baseline: 5.3607x; 1.1300x over previous
//
#include <hip/hip_runtime.h>
#include <cmath>

#define B_ 4
#define S_ 2048
#define D_ 1024
#define H_ 16
#define HD_ 64

typedef __attribute__((ext_vector_type(8))) short short8;
typedef __attribute__((ext_vector_type(4))) float floatx4;
typedef __attribute__((ext_vector_type(16))) float floatx16;

// ---------------- bf16 helpers ----------------
__device__ __forceinline__ unsigned short bf_rne(float x) {
    unsigned u = __float_as_uint(x);
    u += 0x7fffu + ((u >> 16) & 1u);
    return (unsigned short)(u >> 16);
}
__device__ __forceinline__ float bf_to_f(unsigned h) {
    return __uint_as_float(h << 16);
}
__device__ __forceinline__ unsigned bfpack2(float a, float b) {
    return (unsigned)bf_rne(a) | ((unsigned)bf_rne(b) << 16);
}
__device__ __forceinline__ void split_pack8(const float4 a, const float4 b,
                                            uint4& hi, uint4& lo) {
    float xs[8] = {a.x, a.y, a.z, a.w, b.x, b.y, b.z, b.w};
    unsigned h[8], lw[8];
#pragma unroll
    for (int t = 0; t < 8; ++t) {
        unsigned short hh = bf_rne(xs[t]);
        h[t] = hh;
        float r = xs[t] - bf_to_f(hh);   // exact in fp32
        lw[t] = bf_rne(r);
    }
    hi = make_uint4(h[0] | (h[1] << 16), h[2] | (h[3] << 16),
                    h[4] | (h[5] << 16), h[6] | (h[7] << 16));
    lo = make_uint4(lw[0] | (lw[1] << 16), lw[2] | (lw[3] << 16),
                    lw[4] | (lw[5] << 16), lw[6] | (lw[7] << 16));
}

// ---------------- prepass: fp32 -> bf16 hi/lo pair ----------------
__global__ __launch_bounds__(256)
void conv_split(const float* __restrict__ x, unsigned short* __restrict__ hi,
                unsigned short* __restrict__ lo, int n)
{
    const int i = (blockIdx.x * 256 + threadIdx.x) * 8;
    if (i >= n) return;
    const float4 a = *(const float4*)(x + i);
    const float4 b = *(const float4*)(x + i + 4);
    uint4 h, l2;
    split_pack8(a, b, h, l2);
    *(uint4*)(hi + i) = h;
    *(uint4*)(lo + i) = l2;
}

// ---------------- GEMM NT on pre-split bf16 pairs ----------------
// C[M,N] = (Ah+Al)[M,K] * (Bh+Bl)[N,K]^T + bias, acc = hi*hi + hi*lo + lo*hi.
// 128x128 tile, BK=32, 256 thr, frag-ordered LDS (conflict-free ds_read_b128).
// OBF=1 -> bf16 output (QKV projections), else fp32.
template<int OBF>
__global__ __launch_bounds__(256, 2)
void gemm_pair(const unsigned short* __restrict__ Ah_, const unsigned short* __restrict__ Al_,
               const unsigned short* __restrict__ Bh_, const unsigned short* __restrict__ Bl_,
               const float* __restrict__ bias, void* __restrict__ Cout,
               int M, int N, int K)
{
    __shared__ uint4 AH[512];
    __shared__ uint4 AL[512];
    __shared__ uint4 BH[512];
    __shared__ uint4 BL[512];

    const int tid = threadIdx.x;
    const int bm = blockIdx.x * 128;
    const int bn = blockIdx.y * 128;
    const int w = tid >> 6, l = tid & 63;
    const int wm = (w & 1) * 64, wn = (w >> 1) * 64;

    floatx4 acc[4][4];
#pragma unroll
    for (int i = 0; i < 4; ++i)
#pragma unroll
        for (int j = 0; j < 4; ++j)
#pragma unroll
            for (int r = 0; r < 4; ++r) acc[i][j][r] = 0.f;

    // staging: thread -> (row r0 / r0+64, 16B chunk sc of the 32-elem k-slab)
    const int r0 = tid >> 2, sc = tid & 3;
    const size_t a0 = (size_t)(bm + r0) * K + sc * 8;
    const size_t a1 = (size_t)(bm + r0 + 64) * K + sc * 8;
    const size_t b0 = (size_t)(bn + r0) * K + sc * 8;
    const size_t b1 = (size_t)(bn + r0 + 64) * K + sc * 8;
    const int f0 = ((r0 >> 4) << 6) + (sc << 4) + (r0 & 15);
    const int f1 = f0 + 256;

    const short8* pAh = (const short8*)AH;
    const short8* pAl = (const short8*)AL;
    const short8* pBh = (const short8*)BH;
    const short8* pBl = (const short8*)BL;
    const int am = (wm >> 4) * 64 + l;
    const int bnf = (wn >> 4) * 64 + l;

    for (int k0 = 0; k0 < K; k0 += 32) {
        const uint4 vAh0 = *(const uint4*)(Ah_ + a0 + k0);
        const uint4 vAh1 = *(const uint4*)(Ah_ + a1 + k0);
        const uint4 vAl0 = *(const uint4*)(Al_ + a0 + k0);
        const uint4 vAl1 = *(const uint4*)(Al_ + a1 + k0);
        const uint4 vBh0 = *(const uint4*)(Bh_ + b0 + k0);
        const uint4 vBh1 = *(const uint4*)(Bh_ + b1 + k0);
        const uint4 vBl0 = *(const uint4*)(Bl_ + b0 + k0);
        const uint4 vBl1 = *(const uint4*)(Bl_ + b1 + k0);
        __syncthreads();
        AH[f0] = vAh0; AH[f1] = vAh1;
        AL[f0] = vAl0; AL[f1] = vAl1;
        BH[f0] = vBh0; BH[f1] = vBh1;
        BL[f0] = vBl0; BL[f1] = vBl1;
        __syncthreads();

        short8 ah[4], al[4];
#pragma unroll
        for (int i = 0; i < 4; ++i) {
            ah[i] = pAh[am + i * 64];
            al[i] = pAl[am + i * 64];
        }
#pragma unroll
        for (int j = 0; j < 4; ++j) {
            const short8 bh = pBh[bnf + j * 64];
            const short8 bl = pBl[bnf + j * 64];
#pragma unroll
            for (int i = 0; i < 4; ++i) {
                acc[i][j] = __builtin_amdgcn_mfma_f32_16x16x32_bf16(ah[i], bh, acc[i][j], 0, 0, 0);
                acc[i][j] = __builtin_amdgcn_mfma_f32_16x16x32_bf16(ah[i], bl, acc[i][j], 0, 0, 0);
                acc[i][j] = __builtin_amdgcn_mfma_f32_16x16x32_bf16(al[i], bh, acc[i][j], 0, 0, 0);
            }
        }
    }

    const int cr = (l >> 4) << 2;
    const int cc = l & 15;
#pragma unroll
    for (int j = 0; j < 4; ++j) {
        const int col = bn + wn + j * 16 + cc;
        const float bv = bias[col];
#pragma unroll
        for (int i = 0; i < 4; ++i) {
            const int row = bm + wm + i * 16 + cr;
#pragma unroll
            for (int r = 0; r < 4; ++r) {
                const float vv = acc[i][j][r] + bv;
                if (OBF)
                    ((unsigned short*)Cout)[(size_t)(row + r) * N + col] = bf_rne(vv);
                else
                    ((float*)Cout)[(size_t)(row + r) * N + col] = vv;
            }
        }
    }
}

// ---------------- prep: RoPE + repack for Q and K (bf16 in, bf16 out) --------
// Reference quirk: c=sin, s=cos -> out1 = x1*sin - x2*cos; out2 = x2*sin + x1*cos.
// K pre-scaled by 0.125*log2(e) so scores are base-2 exponents (exp2 softmax).
__global__ __launch_bounds__(256)
void prep_qk_kernel(const unsigned short* __restrict__ q, const unsigned short* __restrict__ k,
                    unsigned short* __restrict__ Qb, unsigned short* __restrict__ Kb)
{
    const int bs = blockIdx.x;
    const int s = bs & (S_ - 1);
    const size_t base = (size_t)bs * D_;
    const int t = threadIdx.x;
    const int h = t >> 4;
    const int i2 = (t & 15) * 2;
    const float kfreq = 0.28782313662425572f;   // ln(10000)/32
    const float KS = 0.18033688011112042f;      // 0.125 * log2(e)

    const float f0 = expf(-(float)i2 * kfreq);
    const float f1 = expf(-(float)(i2 + 1) * kfreq);
    const float t0 = (float)s * f0, t1 = (float)s * f1;
    const float sn0 = sinf(t0), cs0 = cosf(t0);
    const float sn1 = sinf(t1), cs1 = cosf(t1);

    const size_t p1 = base + (size_t)h * 64 + i2;
    const size_t p2 = p1 + 32;

    const unsigned uq1 = *(const unsigned*)(q + p1);
    const unsigned uq2 = *(const unsigned*)(q + p2);
    const unsigned uk1 = *(const unsigned*)(k + p1);
    const unsigned uk2 = *(const unsigned*)(k + p2);
    const float q1x = bf_to_f(uq1 & 0xffffu), q1y = bf_to_f(uq1 >> 16);
    const float q2x = bf_to_f(uq2 & 0xffffu), q2y = bf_to_f(uq2 >> 16);
    const float k1x = bf_to_f(uk1 & 0xffffu), k1y = bf_to_f(uk1 >> 16);
    const float k2x = bf_to_f(uk2 & 0xffffu), k2y = bf_to_f(uk2 >> 16);

    *(unsigned*)(Qb + p1) = bfpack2(q1x * sn0 - q2x * cs0, q1y * sn1 - q2y * cs1);
    *(unsigned*)(Qb + p2) = bfpack2(q2x * sn0 + q1x * cs0, q2y * sn1 + q1y * cs1);
    *(unsigned*)(Kb + p1) = bfpack2((k1x * sn0 - k2x * cs0) * KS, (k1y * sn1 - k2y * cs1) * KS);
    *(unsigned*)(Kb + p2) = bfpack2((k2x * sn0 + k1x * cs0) * KS, (k2y * sn1 + k1y * cs1) * KS);
}

// ---------------- V transpose: bf16 (B,S,H*64) -> bf16 Vt (B,H,64,S) ----------
__global__ __launch_bounds__(256)
void v_conv_kernel(const unsigned short* __restrict__ v, unsigned short* __restrict__ Vt)
{
    __shared__ unsigned T[64][65];   // one bf16 per uint cell -> conflict-free column reads
    const int bx = blockIdx.x;
    const int st = bx & 31;
    const int h  = (bx >> 5) & 15;
    const int b  = bx >> 9;
    const int t = threadIdx.x;
    const int s0 = st * 64;

#pragma unroll
    for (int it = 0; it < 2; ++it) {
        const int idx = it * 256 + t;          // 0..511
        const int row = idx >> 3;
        const int c8 = (idx & 7) * 8;
        const uint4 u = *(const uint4*)(v + ((size_t)(b * S_ + s0 + row)) * D_ + h * 64 + c8);
        T[row][c8+0] = u.x & 0xffffu; T[row][c8+1] = u.x >> 16;
        T[row][c8+2] = u.y & 0xffffu; T[row][c8+3] = u.y >> 16;
        T[row][c8+4] = u.z & 0xffffu; T[row][c8+5] = u.z >> 16;
        T[row][c8+6] = u.w & 0xffffu; T[row][c8+7] = u.w >> 16;
    }
    __syncthreads();

    const int d = t >> 2;
    const int scg = (t & 3) * 16;
    unsigned u[8];
#pragma unroll
    for (int ii = 0; ii < 8; ++ii)
        u[ii] = T[scg + 2*ii][d] | (T[scg + 2*ii + 1][d] << 16);
    unsigned short* dst = Vt + ((size_t)((b * H_ + h) * 64 + d)) * S_ + s0 + scg;
    *(uint4*)(dst)     = make_uint4(u[0], u[1], u[2], u[3]);
    *(uint4*)(dst + 8) = make_uint4(u[4], u[5], u[6], u[7]);
}

// ---------------- MFMA flash attention, 32x32 shape, exp2 softmax ----------------
// S^T = K*Q^T (C col = query). No max-subtraction (scores bounded; constant shift
// cancels in p/l). p = exp2(s') with K pre-scaled by 0.125*log2e. P packed RTZ;
// l = ones-row MFMA on the SAME packed P -> normalization exactly consistent.
// P^T B-frags built with one xor-32 shfl hop (32x32 C-layout keeps q on lane&31).
__global__ __launch_bounds__(256)
void attn_mfma32(const unsigned short* __restrict__ Qb,
                 const unsigned short* __restrict__ Kb,
                 const unsigned short* __restrict__ Vt,
                 float* __restrict__ ctx)
{
    __shared__ uint4 KF[512];   // 8 KB: K tile, A-frag order
    __shared__ uint4 VF[512];   // 8 KB: V^T tile, A-frag order

    const int t = threadIdx.x;
    const int bx = blockIdx.x;
    const int qblk = bx & 15, h = (bx >> 4) & 15, b = bx >> 8;
    const int w = t >> 6, l = t & 63;
    const int lq = l & 31, h5 = l >> 5;
    const int qrow = qblk * 128 + w * 32 + lq;

    // Q B-frags (regs, whole kernel): B[k=h5*8+j][n=q], chunks kc=0..3
    short8 qf[4];
    const unsigned short* qp = Qb + ((size_t)(b * S_ + qrow)) * D_ + h * 64 + h5 * 8;
#pragma unroll
    for (int kc = 0; kc < 4; ++kc) qf[kc] = *(const short8*)(qp + kc * 16);

    floatx16 o0, o1, o2, z16;
#pragma unroll
    for (int r = 0; r < 16; ++r) { o0[r] = 0.f; o1[r] = 0.f; o2[r] = 0.f; z16[r] = 0.f; }

    // ones A-frag (row m=0 only) for the l-sum MFMA
    union { unsigned u[4]; short8 s; } onesf;
    const unsigned ov = (lq == 0) ? 0x3f803f80u : 0u;
    onesf.u[0] = ov; onesf.u[1] = ov; onesf.u[2] = ov; onesf.u[3] = ov;

    // staging: thread -> (row sr, 32B chunk sc); same LDS index formula for K and V
    const int sr = t >> 2, sc = t & 3;
    const unsigned short* gK = Kb + ((size_t)(b * S_ + sr)) * D_ + h * 64 + sc * 16;
    const unsigned short* gV = Vt + ((size_t)((b * H_ + h) * 64 + sr)) * S_ + sc * 16;
    const int e0 = (sr >> 5) * 256 + sc * 64 + (sr & 31);

    const short8* pK = (const short8*)KF;
    const short8* pV = (const short8*)VF;

    for (int kt = 0; kt < 32; ++kt) {
        const uint4 ka  = *(const uint4*)(gK);
        const uint4 kb2 = *(const uint4*)(gK + 8);
        const uint4 va  = *(const uint4*)(gV);
        const uint4 vb2 = *(const uint4*)(gV + 8);
        gK += 64 * D_;
        gV += 64;
        __syncthreads();
        KF[e0] = ka; KF[e0 + 32] = kb2;
        VF[e0] = va; VF[e0 + 32] = vb2;
        __syncthreads();

        // S^T tiles (2 x 32 keys): C[key][q], key = (r&3)+8*(r>>2)+4*h5 (+32*t2)
        floatx16 st0 = __builtin_amdgcn_mfma_f32_32x32x16_bf16(pK[l],          qf[0], z16, 0, 0, 0);
        floatx16 st1 = __builtin_amdgcn_mfma_f32_32x32x16_bf16(pK[4 * 64 + l], qf[0], z16, 0, 0, 0);
#pragma unroll
        for (int kc = 1; kc < 4; ++kc) {
            st0 = __builtin_amdgcn_mfma_f32_32x32x16_bf16(pK[kc * 64 + l],       qf[kc], st0, 0, 0, 0);
            st1 = __builtin_amdgcn_mfma_f32_32x32x16_bf16(pK[(4 + kc) * 64 + l], qf[kc], st1, 0, 0, 0);
        }

        // p = exp2(s'), RTZ-pack pairs (bias cancels: l is summed from packed p)
        unsigned pu0[8], pu1[8];
#pragma unroll
        for (int g = 0; g < 8; ++g) {
            const float a0 = __builtin_amdgcn_exp2f(st0[2 * g]);
            const float b0 = __builtin_amdgcn_exp2f(st0[2 * g + 1]);
            pu0[g] = (__float_as_uint(a0) >> 16) | (__float_as_uint(b0) & 0xffff0000u);
            const float a1 = __builtin_amdgcn_exp2f(st1[2 * g]);
            const float b1 = __builtin_amdgcn_exp2f(st1[2 * g + 1]);
            pu1[g] = (__float_as_uint(a1) >> 16) | (__float_as_uint(b1) & 0xffff0000u);
        }

        // PV: O^T += V^T * P^T, plus ones-row for l
#pragma unroll
        for (int kc = 0; kc < 4; ++kc) {
            const unsigned* pus = (kc >> 1) ? pu1 : pu0;
            const int g0 = (kc & 1) * 4;
            const unsigned own0 = h5 ? pus[g0 + 2] : pus[g0 + 0];
            const unsigned srv0 = h5 ? pus[g0 + 0] : pus[g0 + 2];
            const unsigned own1 = h5 ? pus[g0 + 3] : pus[g0 + 1];
            const unsigned srv1 = h5 ? pus[g0 + 1] : pus[g0 + 3];
            const unsigned par0 = (unsigned)__shfl_xor((int)srv0, 32, 64);
            const unsigned par1 = (unsigned)__shfl_xor((int)srv1, 32, 64);
            union { unsigned u[4]; short8 s; } pf;
            pf.u[0] = h5 ? par0 : own0;
            pf.u[1] = h5 ? par1 : own1;
            pf.u[2] = h5 ? own0 : par0;
            pf.u[3] = h5 ? own1 : par1;
            o0 = __builtin_amdgcn_mfma_f32_32x32x16_bf16(pV[kc * 64 + l],       pf.s, o0, 0, 0, 0);
            o1 = __builtin_amdgcn_mfma_f32_32x32x16_bf16(pV[(4 + kc) * 64 + l], pf.s, o1, 0, 0, 0);
            o2 = __builtin_amdgcn_mfma_f32_32x32x16_bf16(onesf.s,               pf.s, o2, 0, 0, 0);
        }
    }

    // l lives in o2 reg0 of h5==0 lanes (C row 0)
    const float lpart = o2[0];
    const float lothr = __shfl_xor(lpart, 32, 64);
    const float lsum = h5 ? lothr : lpart;
    const float inv = 1.0f / lsum;

    float* cp = ctx + ((size_t)(b * S_ + qrow)) * D_ + h * 64;
#pragma unroll
    for (int rq = 0; rq < 4; ++rq) {
        const int d0 = rq * 8 + h5 * 4;
        float4 x0, x1;
        x0.x = o0[4*rq+0] * inv; x0.y = o0[4*rq+1] * inv;
        x0.z = o0[4*rq+2] * inv; x0.w = o0[4*rq+3] * inv;
        x1.x = o1[4*rq+0] * inv; x1.y = o1[4*rq+1] * inv;
        x1.z = o1[4*rq+2] * inv; x1.w = o1[4*rq+3] * inv;
        *(float4*)(cp + d0) = x0;
        *(float4*)(cp + 32 + d0) = x1;
    }
}

extern "C" void kernel_launch(void* const* d_in, const int* in_sizes, int n_in,
                              void* d_out, int out_size, void* d_ws, size_t ws_size,
                              hipStream_t stream) {
    (void)in_sizes; (void)n_in; (void)out_size; (void)ws_size;
    const float* X  = (const float*)d_in[0];
    const float* Wq = (const float*)d_in[1];
    const float* bq = (const float*)d_in[2];
    const float* Wk = (const float*)d_in[3];
    const float* bk = (const float*)d_in[4];
    const float* Wv = (const float*)d_in[5];
    const float* bv = (const float*)d_in[6];
    const float* Wo = (const float*)d_in[7];
    const float* bo = (const float*)d_in[8];
    float* out = (float*)d_out;

    char* ws = (char*)d_ws;
#define OFF(mb) (ws + ((size_t)(mb) << 20))
    unsigned short* qb16 = (unsigned short*)OFF(0);    // 16 MB (dead after prep_qk)
    unsigned short* kb16 = (unsigned short*)OFF(16);   // 16 MB (dead after prep_qk)
    unsigned short* vb16 = (unsigned short*)OFF(32);   // 16 MB (dead after v_conv)
    unsigned short* Xh   = (unsigned short*)OFF(48);   // 16 MB (dead after V-GEMM)
    unsigned short* Xl   = (unsigned short*)OFF(64);   // 16 MB
    unsigned short* Wqh  = (unsigned short*)OFF(80);
    unsigned short* Wql  = (unsigned short*)OFF(82);
    unsigned short* Wkh  = (unsigned short*)OFF(84);
    unsigned short* Wkl  = (unsigned short*)OFF(86);
    unsigned short* Wvh  = (unsigned short*)OFF(88);
    unsigned short* Wvl  = (unsigned short*)OFF(90);
    unsigned short* Woh  = (unsigned short*)OFF(92);
    unsigned short* Wol  = (unsigned short*)OFF(94);
    unsigned short* Qbf  = (unsigned short*)OFF(96);   // 16 MB
    unsigned short* Kbf  = (unsigned short*)OFF(112);  // 16 MB
    unsigned short* Vtb  = (unsigned short*)OFF(128);  // 16 MB
    float* ctx = (float*)OFF(0);                       // 32 MB over qb16+kb16
    unsigned short* Ch = (unsigned short*)OFF(32);     // over vb16
    unsigned short* Cl = (unsigned short*)OFF(48);     // over Xh
#undef OFF

    const int NX = B_ * S_ * D_;   // 8M
    const int NW = D_ * D_;        // 1M
    conv_split<<<NX / 2048, 256, 0, stream>>>(X, Xh, Xl, NX);
    conv_split<<<NW / 2048, 256, 0, stream>>>(Wq, Wqh, Wql, NW);
    conv_split<<<NW / 2048, 256, 0, stream>>>(Wk, Wkh, Wkl, NW);
    conv_split<<<NW / 2048, 256, 0, stream>>>(Wv, Wvh, Wvl, NW);
    conv_split<<<NW / 2048, 256, 0, stream>>>(Wo, Woh, Wol, NW);

    dim3 gridG(64, 8), blockG(256);
    gemm_pair<1><<<gridG, blockG, 0, stream>>>(Xh, Xl, Wqh, Wql, bq, qb16, B_*S_, D_, D_);
    gemm_pair<1><<<gridG, blockG, 0, stream>>>(Xh, Xl, Wkh, Wkl, bk, kb16, B_*S_, D_, D_);
    gemm_pair<1><<<gridG, blockG, 0, stream>>>(Xh, Xl, Wvh, Wvl, bv, vb16, B_*S_, D_, D_);

    prep_qk_kernel<<<B_*S_, 256, 0, stream>>>(qb16, kb16, Qbf, Kbf);
    v_conv_kernel<<<B_*H_*(S_/64), 256, 0, stream>>>(vb16, Vtb);

    attn_mfma32<<<B_*H_*(S_/128), 256, 0, stream>>>(Qbf, Kbf, Vtb, ctx);

    conv_split<<<NX / 2048, 256, 0, stream>>>(ctx, Ch, Cl, NX);
    gemm_pair<0><<<gridG, blockG, 0, stream>>>(Ch, Cl, Woh, Wol, bo, out, B_*S_, D_, D_);
}

// Round 6
// 453.360 us; speedup vs baseline: 6.1911x; 1.1549x over previous
//
#include <hip/hip_runtime.h>
#include <cmath>

#define B_ 4
#define S_ 2048
#define D_ 1024
#define H_ 16
#define HD_ 64

typedef __attribute__((ext_vector_type(8))) short short8;
typedef __attribute__((ext_vector_type(4))) float floatx4;
typedef __attribute__((ext_vector_type(16))) float floatx16;

// ---------------- bf16 helpers ----------------
__device__ __forceinline__ unsigned short bf_rne(float x) {
    unsigned u = __float_as_uint(x);
    u += 0x7fffu + ((u >> 16) & 1u);
    return (unsigned short)(u >> 16);
}
__device__ __forceinline__ float bf_to_f(unsigned h) {
    return __uint_as_float(h << 16);
}
__device__ __forceinline__ unsigned bfpack2(float a, float b) {
    return (unsigned)bf_rne(a) | ((unsigned)bf_rne(b) << 16);
}
__device__ __forceinline__ void split_pack8(const float4 a, const float4 b,
                                            uint4& hi, uint4& lo) {
    float xs[8] = {a.x, a.y, a.z, a.w, b.x, b.y, b.z, b.w};
    unsigned h[8], lw[8];
#pragma unroll
    for (int t = 0; t < 8; ++t) {
        unsigned short hh = bf_rne(xs[t]);
        h[t] = hh;
        float r = xs[t] - bf_to_f(hh);   // exact in fp32
        lw[t] = bf_rne(r);
    }
    hi = make_uint4(h[0] | (h[1] << 16), h[2] | (h[3] << 16),
                    h[4] | (h[5] << 16), h[6] | (h[7] << 16));
    lo = make_uint4(lw[0] | (lw[1] << 16), lw[2] | (lw[3] << 16),
                    lw[4] | (lw[5] << 16), lw[6] | (lw[7] << 16));
}
__device__ __forceinline__ void split_pack4(const float* x, uint2& hi, uint2& lo) {
    unsigned h[4], lw[4];
#pragma unroll
    for (int t = 0; t < 4; ++t) {
        h[t] = bf_rne(x[t]);
        lw[t] = bf_rne(x[t] - bf_to_f(h[t]));
    }
    hi = make_uint2(h[0] | (h[1] << 16), h[2] | (h[3] << 16));
    lo = make_uint2(lw[0] | (lw[1] << 16), lw[2] | (lw[3] << 16));
}

// ---------------- prepass: X fp32 -> bf16 hi/lo pair ----------------
__global__ __launch_bounds__(256)
void conv_x(const float* __restrict__ x, unsigned short* __restrict__ hi,
            unsigned short* __restrict__ lo, int n)
{
    const int i = (blockIdx.x * 256 + threadIdx.x) * 8;
    if (i >= n) return;
    const float4 a = *(const float4*)(x + i);
    const float4 b = *(const float4*)(x + i + 4);
    uint4 h, l2;
    split_pack8(a, b, h, l2);
    *(uint4*)(hi + i) = h;
    *(uint4*)(lo + i) = l2;
}

// ---------------- prepass: all 4 weights -> split pairs, biases -> packed ----
// Wq,Wk,Wv -> Wqkv[3072,1024] (rows 0-1023=q, 1024-2047=k, 2048-3071=v);
// Wo -> Woh/Wol; bq|bk|bv -> bqkv[3072].
__global__ __launch_bounds__(256)
void conv_weights(const float* __restrict__ Wq, const float* __restrict__ Wk,
                  const float* __restrict__ Wv, const float* __restrict__ Wo,
                  const float* __restrict__ bq, const float* __restrict__ bk,
                  const float* __restrict__ bv,
                  unsigned short* __restrict__ Wqkvh, unsigned short* __restrict__ Wqkvl,
                  unsigned short* __restrict__ Woh, unsigned short* __restrict__ Wol,
                  float* __restrict__ bqkv)
{
    const int bxx = blockIdx.x;
    const int t = threadIdx.x;
    if (bxx < 2048) {
        const int w = bxx >> 9;
        const int i = ((bxx & 511) * 256 + t) * 8;
        const float* src = (w == 0) ? Wq : (w == 1) ? Wk : (w == 2) ? Wv : Wo;
        const float4 a = *(const float4*)(src + i);
        const float4 b = *(const float4*)(src + i + 4);
        uint4 hv, lv;
        split_pack8(a, b, hv, lv);
        if (w < 3) {
            *(uint4*)(Wqkvh + (size_t)w * 1048576 + i) = hv;
            *(uint4*)(Wqkvl + (size_t)w * 1048576 + i) = lv;
        } else {
            *(uint4*)(Woh + i) = hv;
            *(uint4*)(Wol + i) = lv;
        }
    } else {
        const int idx = t * 4;
        *(float4*)(bqkv + idx)        = *(const float4*)(bq + idx);
        *(float4*)(bqkv + 1024 + idx) = *(const float4*)(bk + idx);
        *(float4*)(bqkv + 2048 + idx) = *(const float4*)(bv + idx);
    }
}

// ---------------- GEMM NT on pre-split bf16 pairs, register-prefetch pipelined --
// C[M,N] = (Ah+Al)(Bh+Bl)^T + bias; acc = hh + hl + lh. 128x128 tile, BK=32.
// Next k-tile is loaded into VGPRs while the current tile's MFMAs run.
template<int OBF>
__global__ __launch_bounds__(256, 2)
void gemm_pair(const unsigned short* __restrict__ Ah_, const unsigned short* __restrict__ Al_,
               const unsigned short* __restrict__ Bh_, const unsigned short* __restrict__ Bl_,
               const float* __restrict__ bias, void* __restrict__ Cout,
               int M, int N, int K)
{
    __shared__ uint4 AH[512];
    __shared__ uint4 AL[512];
    __shared__ uint4 BH[512];
    __shared__ uint4 BL[512];

    const int tid = threadIdx.x;
    const int bm = blockIdx.x * 128;
    const int bn = blockIdx.y * 128;
    const int w = tid >> 6, l = tid & 63;
    const int wm = (w & 1) * 64, wn = (w >> 1) * 64;

    floatx4 acc[4][4];
#pragma unroll
    for (int i = 0; i < 4; ++i)
#pragma unroll
        for (int j = 0; j < 4; ++j)
#pragma unroll
            for (int r = 0; r < 4; ++r) acc[i][j][r] = 0.f;

    const int r0 = tid >> 2, sc = tid & 3;
    const size_t a0 = (size_t)(bm + r0) * K + sc * 8;
    const size_t a1 = (size_t)(bm + r0 + 64) * K + sc * 8;
    const size_t b0 = (size_t)(bn + r0) * K + sc * 8;
    const size_t b1 = (size_t)(bn + r0 + 64) * K + sc * 8;
    const int f0 = ((r0 >> 4) << 6) + (sc << 4) + (r0 & 15);
    const int f1 = f0 + 256;

    const short8* pAh = (const short8*)AH;
    const short8* pAl = (const short8*)AL;
    const short8* pBh = (const short8*)BH;
    const short8* pBl = (const short8*)BL;
    const int am = (wm >> 4) * 64 + l;
    const int bnf = (wn >> 4) * 64 + l;

    // prefetch k-tile 0
    uint4 vAh0 = *(const uint4*)(Ah_ + a0);
    uint4 vAh1 = *(const uint4*)(Ah_ + a1);
    uint4 vAl0 = *(const uint4*)(Al_ + a0);
    uint4 vAl1 = *(const uint4*)(Al_ + a1);
    uint4 vBh0 = *(const uint4*)(Bh_ + b0);
    uint4 vBh1 = *(const uint4*)(Bh_ + b1);
    uint4 vBl0 = *(const uint4*)(Bl_ + b0);
    uint4 vBl1 = *(const uint4*)(Bl_ + b1);

    for (int k0 = 0; k0 < K; k0 += 32) {
        __syncthreads();
        AH[f0] = vAh0; AH[f1] = vAh1;
        AL[f0] = vAl0; AL[f1] = vAl1;
        BH[f0] = vBh0; BH[f1] = vBh1;
        BL[f0] = vBl0; BL[f1] = vBl1;
        __syncthreads();

        // issue next tile's loads (branchless clamp; last iter reloads same tile)
        const int kn = (k0 + 32 < K) ? k0 + 32 : k0;
        vAh0 = *(const uint4*)(Ah_ + a0 + kn);
        vAh1 = *(const uint4*)(Ah_ + a1 + kn);
        vAl0 = *(const uint4*)(Al_ + a0 + kn);
        vAl1 = *(const uint4*)(Al_ + a1 + kn);
        vBh0 = *(const uint4*)(Bh_ + b0 + kn);
        vBh1 = *(const uint4*)(Bh_ + b1 + kn);
        vBl0 = *(const uint4*)(Bl_ + b0 + kn);
        vBl1 = *(const uint4*)(Bl_ + b1 + kn);

        short8 ah[4], al[4];
#pragma unroll
        for (int i = 0; i < 4; ++i) {
            ah[i] = pAh[am + i * 64];
            al[i] = pAl[am + i * 64];
        }
#pragma unroll
        for (int j = 0; j < 4; ++j) {
            const short8 bh = pBh[bnf + j * 64];
            const short8 bl = pBl[bnf + j * 64];
#pragma unroll
            for (int i = 0; i < 4; ++i) {
                acc[i][j] = __builtin_amdgcn_mfma_f32_16x16x32_bf16(ah[i], bh, acc[i][j], 0, 0, 0);
                acc[i][j] = __builtin_amdgcn_mfma_f32_16x16x32_bf16(ah[i], bl, acc[i][j], 0, 0, 0);
                acc[i][j] = __builtin_amdgcn_mfma_f32_16x16x32_bf16(al[i], bh, acc[i][j], 0, 0, 0);
            }
        }
    }

    const int cr = (l >> 4) << 2;
    const int cc = l & 15;
#pragma unroll
    for (int j = 0; j < 4; ++j) {
        const int col = bn + wn + j * 16 + cc;
        const float bv = bias[col];
#pragma unroll
        for (int i = 0; i < 4; ++i) {
            const int row = bm + wm + i * 16 + cr;
#pragma unroll
            for (int r = 0; r < 4; ++r) {
                const float vv = acc[i][j][r] + bv;
                if (OBF)
                    ((unsigned short*)Cout)[(size_t)(row + r) * N + col] = bf_rne(vv);
                else
                    ((float*)Cout)[(size_t)(row + r) * N + col] = vv;
            }
        }
    }
}

// ---------------- fused prep: RoPE(Q,K) + V transpose, from packed qkv16 -----
// qkv16 is bf16 [B*S, 3072] (q|k|v). Blocks [0,B*S): RoPE -> Qb,Kb (B,S,D),
// K pre-scaled by 0.125*log2e. Blocks [B*S, B*S+2048): V -> Vt (B,H,64,S).
// Reference quirk: c=sin, s=cos -> out1 = x1*sin - x2*cos; out2 = x2*sin + x1*cos.
__global__ __launch_bounds__(256)
void prep_fused(const unsigned short* __restrict__ qkv,
                unsigned short* __restrict__ Qb, unsigned short* __restrict__ Kb,
                unsigned short* __restrict__ Vt)
{
    __shared__ unsigned T[64][65];
    const int bx = blockIdx.x;
    const int t = threadIdx.x;
    if (bx < B_ * S_) {
        const int bs = bx;
        const int s = bs & (S_ - 1);
        const size_t rbase = (size_t)bs * 3072;
        const size_t obase = (size_t)bs * D_;
        const int h = t >> 4;
        const int i2 = (t & 15) * 2;
        const float kfreq = 0.28782313662425572f;   // ln(10000)/32
        const float KS = 0.18033688011112042f;      // 0.125 * log2(e)

        const float f0 = expf(-(float)i2 * kfreq);
        const float f1 = expf(-(float)(i2 + 1) * kfreq);
        const float t0 = (float)s * f0, t1 = (float)s * f1;
        const float sn0 = sinf(t0), cs0 = cosf(t0);
        const float sn1 = sinf(t1), cs1 = cosf(t1);

        const size_t c1 = (size_t)h * 64 + i2;
        const size_t c2 = c1 + 32;

        const unsigned uq1 = *(const unsigned*)(qkv + rbase + c1);
        const unsigned uq2 = *(const unsigned*)(qkv + rbase + c2);
        const unsigned uk1 = *(const unsigned*)(qkv + rbase + 1024 + c1);
        const unsigned uk2 = *(const unsigned*)(qkv + rbase + 1024 + c2);
        const float q1x = bf_to_f(uq1 & 0xffffu), q1y = bf_to_f(uq1 >> 16);
        const float q2x = bf_to_f(uq2 & 0xffffu), q2y = bf_to_f(uq2 >> 16);
        const float k1x = bf_to_f(uk1 & 0xffffu), k1y = bf_to_f(uk1 >> 16);
        const float k2x = bf_to_f(uk2 & 0xffffu), k2y = bf_to_f(uk2 >> 16);

        *(unsigned*)(Qb + obase + c1) = bfpack2(q1x * sn0 - q2x * cs0, q1y * sn1 - q2y * cs1);
        *(unsigned*)(Qb + obase + c2) = bfpack2(q2x * sn0 + q1x * cs0, q2y * sn1 + q1y * cs1);
        *(unsigned*)(Kb + obase + c1) = bfpack2((k1x * sn0 - k2x * cs0) * KS, (k1y * sn1 - k2y * cs1) * KS);
        *(unsigned*)(Kb + obase + c2) = bfpack2((k2x * sn0 + k1x * cs0) * KS, (k2y * sn1 + k1y * cs1) * KS);
    } else {
        const int vb = bx - B_ * S_;
        const int st = vb & 31;
        const int h  = (vb >> 5) & 15;
        const int b  = vb >> 9;
        const int s0 = st * 64;
#pragma unroll
        for (int it = 0; it < 2; ++it) {
            const int idx = it * 256 + t;
            const int row = idx >> 3;
            const int c8 = (idx & 7) * 8;
            const uint4 u = *(const uint4*)(qkv + ((size_t)(b * S_ + s0 + row)) * 3072 + 2048 + h * 64 + c8);
            T[row][c8+0] = u.x & 0xffffu; T[row][c8+1] = u.x >> 16;
            T[row][c8+2] = u.y & 0xffffu; T[row][c8+3] = u.y >> 16;
            T[row][c8+4] = u.z & 0xffffu; T[row][c8+5] = u.z >> 16;
            T[row][c8+6] = u.w & 0xffffu; T[row][c8+7] = u.w >> 16;
        }
        __syncthreads();
        const int d = t >> 2;
        const int scg = (t & 3) * 16;
        unsigned u[8];
#pragma unroll
        for (int ii = 0; ii < 8; ++ii)
            u[ii] = T[scg + 2*ii][d] | (T[scg + 2*ii + 1][d] << 16);
        unsigned short* dst = Vt + ((size_t)((b * H_ + h) * 64 + d)) * S_ + s0 + scg;
        *(uint4*)(dst)     = make_uint4(u[0], u[1], u[2], u[3]);
        *(uint4*)(dst + 8) = make_uint4(u[4], u[5], u[6], u[7]);
    }
}

// ---------------- MFMA flash attention, pipelined + XCD-swizzled ----------------
// S^T = K*Q^T (C col = query); exp2 softmax, no max-subtraction; l via ones-row
// MFMA on the RTZ-packed P (exactly consistent). Epilogue splits ctx to bf16
// hi/lo pairs for the O-projection. K/V tile kt+1 prefetched into VGPRs during
// compute of kt. Block swizzle: runs of 16 same-(b,h) blocks per XCD.
__global__ __launch_bounds__(256)
void attn_mfma32(const unsigned short* __restrict__ Qb,
                 const unsigned short* __restrict__ Kb,
                 const unsigned short* __restrict__ Vt,
                 unsigned short* __restrict__ Ch,
                 unsigned short* __restrict__ Cl)
{
    __shared__ uint4 KF[512];   // 8 KB: K tile, A-frag order
    __shared__ uint4 VF[512];   // 8 KB: V^T tile, A-frag order

    const int t = threadIdx.x;
    const int i = blockIdx.x;                // [0, 1024)
    const int xcd = i & 7, j = i >> 3;       // j in [0,128)
    const int bh = xcd * 8 + (j >> 4);       // [0,64): 8 (b,h) pairs per XCD
    const int qblk = j & 15;
    const int b = bh >> 4, h = bh & 15;

    const int w = t >> 6, l = t & 63;
    const int lq = l & 31, h5 = l >> 5;
    const int qrow = qblk * 128 + w * 32 + lq;

    short8 qf[4];
    const unsigned short* qp = Qb + ((size_t)(b * S_ + qrow)) * D_ + h * 64 + h5 * 8;
#pragma unroll
    for (int kc = 0; kc < 4; ++kc) qf[kc] = *(const short8*)(qp + kc * 16);

    floatx16 o0, o1, o2, z16;
#pragma unroll
    for (int r = 0; r < 16; ++r) { o0[r] = 0.f; o1[r] = 0.f; o2[r] = 0.f; z16[r] = 0.f; }

    union { unsigned u[4]; short8 s; } onesf;
    const unsigned ov = (lq == 0) ? 0x3f803f80u : 0u;
    onesf.u[0] = ov; onesf.u[1] = ov; onesf.u[2] = ov; onesf.u[3] = ov;

    const int sr = t >> 2, sc = t & 3;
    const unsigned short* gK0 = Kb + ((size_t)(b * S_ + sr)) * D_ + h * 64 + sc * 16;
    const unsigned short* gV0 = Vt + ((size_t)((b * H_ + h) * 64 + sr)) * S_ + sc * 16;
    const int e0 = (sr >> 5) * 256 + sc * 64 + (sr & 31);

    const short8* pK = (const short8*)KF;
    const short8* pV = (const short8*)VF;

    // prefetch k-tile 0
    uint4 ka  = *(const uint4*)(gK0);
    uint4 kb2 = *(const uint4*)(gK0 + 8);
    uint4 va  = *(const uint4*)(gV0);
    uint4 vb2 = *(const uint4*)(gV0 + 8);

    for (int kt = 0; kt < 32; ++kt) {
        __syncthreads();
        KF[e0] = ka; KF[e0 + 32] = kb2;
        VF[e0] = va; VF[e0 + 32] = vb2;
        __syncthreads();

        // prefetch next tile (clamped; last iter harmlessly reloads tile 31)
        const int kn = (kt < 31) ? kt + 1 : kt;
        const unsigned short* gK = gK0 + (size_t)kn * 64 * D_;
        const unsigned short* gV = gV0 + (size_t)kn * 64;
        ka  = *(const uint4*)(gK);
        kb2 = *(const uint4*)(gK + 8);
        va  = *(const uint4*)(gV);
        vb2 = *(const uint4*)(gV + 8);

        floatx16 st0 = __builtin_amdgcn_mfma_f32_32x32x16_bf16(pK[l],          qf[0], z16, 0, 0, 0);
        floatx16 st1 = __builtin_amdgcn_mfma_f32_32x32x16_bf16(pK[4 * 64 + l], qf[0], z16, 0, 0, 0);
#pragma unroll
        for (int kc = 1; kc < 4; ++kc) {
            st0 = __builtin_amdgcn_mfma_f32_32x32x16_bf16(pK[kc * 64 + l],       qf[kc], st0, 0, 0, 0);
            st1 = __builtin_amdgcn_mfma_f32_32x32x16_bf16(pK[(4 + kc) * 64 + l], qf[kc], st1, 0, 0, 0);
        }

        unsigned pu0[8], pu1[8];
#pragma unroll
        for (int g = 0; g < 8; ++g) {
            const float a0 = __builtin_amdgcn_exp2f(st0[2 * g]);
            const float b0 = __builtin_amdgcn_exp2f(st0[2 * g + 1]);
            pu0[g] = (__float_as_uint(a0) >> 16) | (__float_as_uint(b0) & 0xffff0000u);
            const float a1 = __builtin_amdgcn_exp2f(st1[2 * g]);
            const float b1 = __builtin_amdgcn_exp2f(st1[2 * g + 1]);
            pu1[g] = (__float_as_uint(a1) >> 16) | (__float_as_uint(b1) & 0xffff0000u);
        }

#pragma unroll
        for (int kc = 0; kc < 4; ++kc) {
            const unsigned* pus = (kc >> 1) ? pu1 : pu0;
            const int g0 = (kc & 1) * 4;
            const unsigned own0 = h5 ? pus[g0 + 2] : pus[g0 + 0];
            const unsigned srv0 = h5 ? pus[g0 + 0] : pus[g0 + 2];
            const unsigned own1 = h5 ? pus[g0 + 3] : pus[g0 + 1];
            const unsigned srv1 = h5 ? pus[g0 + 1] : pus[g0 + 3];
            const unsigned par0 = (unsigned)__shfl_xor((int)srv0, 32, 64);
            const unsigned par1 = (unsigned)__shfl_xor((int)srv1, 32, 64);
            union { unsigned u[4]; short8 s; } pf;
            pf.u[0] = h5 ? par0 : own0;
            pf.u[1] = h5 ? par1 : own1;
            pf.u[2] = h5 ? own0 : par0;
            pf.u[3] = h5 ? own1 : par1;
            o0 = __builtin_amdgcn_mfma_f32_32x32x16_bf16(pV[kc * 64 + l],       pf.s, o0, 0, 0, 0);
            o1 = __builtin_amdgcn_mfma_f32_32x32x16_bf16(pV[(4 + kc) * 64 + l], pf.s, o1, 0, 0, 0);
            o2 = __builtin_amdgcn_mfma_f32_32x32x16_bf16(onesf.s,               pf.s, o2, 0, 0, 0);
        }
    }

    const float lpart = o2[0];
    const float lothr = __shfl_xor(lpart, 32, 64);
    const float lsum = h5 ? lothr : lpart;
    const float inv = 1.0f / lsum;

    const size_t cbase = ((size_t)(b * S_ + qrow)) * D_ + h * 64;
#pragma unroll
    for (int rq = 0; rq < 4; ++rq) {
        const int d0 = rq * 8 + h5 * 4;
        float x0[4], x1[4];
#pragma unroll
        for (int r = 0; r < 4; ++r) {
            x0[r] = o0[4*rq+r] * inv;
            x1[r] = o1[4*rq+r] * inv;
        }
        uint2 h0, l0, h1, l1;
        split_pack4(x0, h0, l0);
        split_pack4(x1, h1, l1);
        *(uint2*)(Ch + cbase + d0)      = h0;
        *(uint2*)(Cl + cbase + d0)      = l0;
        *(uint2*)(Ch + cbase + 32 + d0) = h1;
        *(uint2*)(Cl + cbase + 32 + d0) = l1;
    }
}

extern "C" void kernel_launch(void* const* d_in, const int* in_sizes, int n_in,
                              void* d_out, int out_size, void* d_ws, size_t ws_size,
                              hipStream_t stream) {
    (void)in_sizes; (void)n_in; (void)out_size; (void)ws_size;
    const float* X  = (const float*)d_in[0];
    const float* Wq = (const float*)d_in[1];
    const float* bq = (const float*)d_in[2];
    const float* Wk = (const float*)d_in[3];
    const float* bk = (const float*)d_in[4];
    const float* Wv = (const float*)d_in[5];
    const float* bv = (const float*)d_in[6];
    const float* Wo = (const float*)d_in[7];
    const float* bo = (const float*)d_in[8];
    float* out = (float*)d_out;

    char* ws = (char*)d_ws;
#define OFF(mb) (ws + ((size_t)(mb) << 20))
    unsigned short* Xh    = (unsigned short*)OFF(0);    // 16 MB (dead after QKV GEMM)
    unsigned short* Xl    = (unsigned short*)OFF(16);   // 16 MB
    unsigned short* qkv16 = (unsigned short*)OFF(32);   // 48 MB (dead after prep)
    unsigned short* Qbf   = (unsigned short*)OFF(80);   // 16 MB
    unsigned short* Kbf   = (unsigned short*)OFF(96);   // 16 MB
    unsigned short* Vtb   = (unsigned short*)OFF(112);  // 16 MB
    float*          bqkv  = (float*)OFF(126);           // 12 KB in Vtb region (dead before Vtb written)
    unsigned short* Wqkvh = (unsigned short*)OFF(128);  // 6 MB
    unsigned short* Wqkvl = (unsigned short*)OFF(134);  // 6 MB
    unsigned short* Woh   = (unsigned short*)OFF(140);  // 2 MB
    unsigned short* Wol   = (unsigned short*)OFF(142);  // 2 MB (ends at 144)
    unsigned short* Ch    = (unsigned short*)OFF(0);    // overlay Xh
    unsigned short* Cl    = (unsigned short*)OFF(16);   // overlay Xl
#undef OFF

    const int NX = B_ * S_ * D_;   // 8M
    conv_x<<<NX / 2048, 256, 0, stream>>>(X, Xh, Xl, NX);
    conv_weights<<<2049, 256, 0, stream>>>(Wq, Wk, Wv, Wo, bq, bk, bv,
                                           Wqkvh, Wqkvl, Woh, Wol, bqkv);
    gemm_pair<1><<<dim3(64, 24), 256, 0, stream>>>(Xh, Xl, Wqkvh, Wqkvl, bqkv,
                                                   qkv16, B_*S_, 3 * D_, D_);
    prep_fused<<<B_*S_ + 2048, 256, 0, stream>>>(qkv16, Qbf, Kbf, Vtb);
    attn_mfma32<<<1024, 256, 0, stream>>>(Qbf, Kbf, Vtb, Ch, Cl);
    gemm_pair<0><<<dim3(64, 8), 256, 0, stream>>>(Ch, Cl, Woh, Wol, bo,
                                                  out, B_*S_, D_, D_);
}

// Round 9
// 335.591 us; speedup vs baseline: 8.3638x; 1.3509x over previous
//
#include <hip/hip_runtime.h>
#include <cmath>

#define B_ 4
#define S_ 2048
#define D_ 1024
#define H_ 16
#define HD_ 64

typedef __attribute__((ext_vector_type(8))) _Float16 half8;
typedef __attribute__((ext_vector_type(2))) _Float16 half2t;
typedef __attribute__((ext_vector_type(2))) __fp16 fp16x2;
typedef __attribute__((ext_vector_type(4))) float floatx4;
typedef __attribute__((ext_vector_type(16))) float floatx16;

// ---------------- fp16 helpers ----------------
union H2U { unsigned u; half2t h; fp16x2 f; };
__device__ __forceinline__ unsigned hpack2(float a, float b) {   // RNE
    H2U x; x.h[0] = (_Float16)a; x.h[1] = (_Float16)b; return x.u;
}
__device__ __forceinline__ unsigned pkrtz(float a, float b) {    // RTZ, 1 instr
    H2U x; x.f = __builtin_amdgcn_cvt_pkrtz(a, b); return x.u;
}
__device__ __forceinline__ float h_lo(unsigned u) { H2U x; x.u = u; return (float)x.h[0]; }
__device__ __forceinline__ float h_hi(unsigned u) { H2U x; x.u = u; return (float)x.h[1]; }

// ---------------- prepass: X fp32 -> fp16 ----------------
__global__ __launch_bounds__(256)
void conv_x(const float* __restrict__ x, unsigned short* __restrict__ o, int n)
{
    const int i = (blockIdx.x * 256 + threadIdx.x) * 8;
    if (i >= n) return;
    const float4 a = *(const float4*)(x + i);
    const float4 b = *(const float4*)(x + i + 4);
    *(uint4*)(o + i) = make_uint4(hpack2(a.x, a.y), hpack2(a.z, a.w),
                                  hpack2(b.x, b.y), hpack2(b.z, b.w));
}

// ---------------- prepass: weights -> fp16, biases -> packed ----------------
// Wq,Wk,Wv -> Wqkv[3072,1024]; Wo -> Wof; bq|bk|bv -> bqkv[3072].
__global__ __launch_bounds__(256)
void conv_weights(const float* __restrict__ Wq, const float* __restrict__ Wk,
                  const float* __restrict__ Wv, const float* __restrict__ Wo,
                  const float* __restrict__ bq, const float* __restrict__ bk,
                  const float* __restrict__ bv,
                  unsigned short* __restrict__ Wqkvf, unsigned short* __restrict__ Wof,
                  float* __restrict__ bqkv)
{
    const int bxx = blockIdx.x;
    const int t = threadIdx.x;
    if (bxx < 2048) {
        const int w = bxx >> 9;
        const int i = ((bxx & 511) * 256 + t) * 8;
        const float* src = (w == 0) ? Wq : (w == 1) ? Wk : (w == 2) ? Wv : Wo;
        const float4 a = *(const float4*)(src + i);
        const float4 b = *(const float4*)(src + i + 4);
        const uint4 v = make_uint4(hpack2(a.x, a.y), hpack2(a.z, a.w),
                                   hpack2(b.x, b.y), hpack2(b.z, b.w));
        if (w < 3)
            *(uint4*)(Wqkvf + (size_t)w * 1048576 + i) = v;
        else
            *(uint4*)(Wof + i) = v;
    } else {
        const int idx = t * 4;
        *(float4*)(bqkv + idx)        = *(const float4*)(bq + idx);
        *(float4*)(bqkv + 1024 + idx) = *(const float4*)(bk + idx);
        *(float4*)(bqkv + 2048 + idx) = *(const float4*)(bv + idx);
    }
}

// ---------------- GEMM NT, fp16 single-pass MFMA, register-prefetch ----------
// C[M,N] = A[M,K] * B[N,K]^T + bias. 128x128 tile, BK=32, 256 thr.
// Frag-ordered LDS (conflict-free ds_read_b128). OBF=1 -> fp16 out, else fp32.
template<int OBF>
__global__ __launch_bounds__(256, 2)
void gemm_half(const unsigned short* __restrict__ Ap, const unsigned short* __restrict__ Bp,
               const float* __restrict__ bias, void* __restrict__ Cout,
               int M, int N, int K)
{
    __shared__ uint4 ASH[512];
    __shared__ uint4 BSH[512];

    const int tid = threadIdx.x;
    const int bm = blockIdx.x * 128;
    const int bn = blockIdx.y * 128;
    const int w = tid >> 6, l = tid & 63;
    const int wm = (w & 1) * 64, wn = (w >> 1) * 64;

    floatx4 acc[4][4];
#pragma unroll
    for (int i = 0; i < 4; ++i)
#pragma unroll
        for (int j = 0; j < 4; ++j)
#pragma unroll
            for (int r = 0; r < 4; ++r) acc[i][j][r] = 0.f;

    // staging: thread t -> row r = t>>1, k-chunks sc = (t&1)*2 + {0,1} (32B contig)
    const int r0 = tid >> 1, scb = (tid & 1) * 2;
    const size_t ga = (size_t)(bm + r0) * K + scb * 8;
    const size_t gb = (size_t)(bn + r0) * K + scb * 8;
    const int f0 = ((r0 >> 4) << 6) + (scb << 4) + (r0 & 15);   // frag for sc=scb
    // frag for sc=scb+1 is f0+16

    const half8* pA = (const half8*)ASH;
    const half8* pB = (const half8*)BSH;
    const int am = (wm >> 4) * 64 + l;
    const int bnf = (wn >> 4) * 64 + l;

    // prefetch k-tile 0
    uint4 vA0 = *(const uint4*)(Ap + ga);
    uint4 vA1 = *(const uint4*)(Ap + ga + 8);
    uint4 vB0 = *(const uint4*)(Bp + gb);
    uint4 vB1 = *(const uint4*)(Bp + gb + 8);

    for (int k0 = 0; k0 < K; k0 += 32) {
        __syncthreads();
        ASH[f0] = vA0; ASH[f0 + 16] = vA1;
        BSH[f0] = vB0; BSH[f0 + 16] = vB1;
        __syncthreads();

        const int kn = (k0 + 32 < K) ? k0 + 32 : k0;
        vA0 = *(const uint4*)(Ap + ga + kn);
        vA1 = *(const uint4*)(Ap + ga + kn + 8);
        vB0 = *(const uint4*)(Bp + gb + kn);
        vB1 = *(const uint4*)(Bp + gb + kn + 8);

        half8 a[4];
#pragma unroll
        for (int i = 0; i < 4; ++i) a[i] = pA[am + i * 64];
#pragma unroll
        for (int j = 0; j < 4; ++j) {
            const half8 b = pB[bnf + j * 64];
#pragma unroll
            for (int i = 0; i < 4; ++i)
                acc[i][j] = __builtin_amdgcn_mfma_f32_16x16x32_f16(a[i], b, acc[i][j], 0, 0, 0);
        }
    }

    // epilogue: C/D layout col=lane&15, row=(lane>>4)*4+reg
    const int cr = (l >> 4) << 2;
    const int cc = l & 15;
#pragma unroll
    for (int j = 0; j < 4; ++j) {
        const int col = bn + wn + j * 16 + cc;
        const float bv = bias[col];
#pragma unroll
        for (int i = 0; i < 4; ++i) {
            const int row = bm + wm + i * 16 + cr;
#pragma unroll
            for (int r = 0; r < 4; ++r) {
                const float vv = acc[i][j][r] + bv;
                if (OBF) {
                    ((unsigned short*)Cout)[(size_t)(row + r) * N + col] =
                        (unsigned short)(hpack2(vv, vv) & 0xffffu);
                } else {
                    ((float*)Cout)[(size_t)(row + r) * N + col] = vv;
                }
            }
        }
    }
}

// ---------------- fused prep: RoPE(Q,K) + V transpose, fp16 ----------------
// qkv fp16 [B*S,3072]. Blocks [0,B*S): RoPE -> Qf,Kf (B,S,D); K scaled by
// 0.125*log2e (exp2 softmax). Blocks [B*S,+2048): V -> Vt (B,H,64,S).
// Reference quirk: c=sin, s=cos -> out1 = x1*sin - x2*cos; out2 = x2*sin + x1*cos.
__global__ __launch_bounds__(256)
void prep_fused(const unsigned short* __restrict__ qkv,
                unsigned short* __restrict__ Qf, unsigned short* __restrict__ Kfo,
                unsigned short* __restrict__ Vt)
{
    __shared__ unsigned T[64][65];
    const int bx = blockIdx.x;
    const int t = threadIdx.x;
    if (bx < B_ * S_) {
        const int s = bx & (S_ - 1);
        const size_t rbase = (size_t)bx * 3072;
        const size_t obase = (size_t)bx * D_;
        const int h = t >> 4;
        const int i2 = (t & 15) * 2;
        const float kfreq = 0.28782313662425572f;   // ln(10000)/32
        const float KS = 0.18033688011112042f;      // 0.125 * log2(e)

        const float f0 = expf(-(float)i2 * kfreq);
        const float f1 = expf(-(float)(i2 + 1) * kfreq);
        const float t0 = (float)s * f0, t1 = (float)s * f1;
        const float sn0 = sinf(t0), cs0 = cosf(t0);
        const float sn1 = sinf(t1), cs1 = cosf(t1);

        const size_t c1 = (size_t)h * 64 + i2;
        const size_t c2 = c1 + 32;

        const unsigned uq1 = *(const unsigned*)(qkv + rbase + c1);
        const unsigned uq2 = *(const unsigned*)(qkv + rbase + c2);
        const unsigned uk1 = *(const unsigned*)(qkv + rbase + 1024 + c1);
        const unsigned uk2 = *(const unsigned*)(qkv + rbase + 1024 + c2);
        const float q1x = h_lo(uq1), q1y = h_hi(uq1);
        const float q2x = h_lo(uq2), q2y = h_hi(uq2);
        const float k1x = h_lo(uk1), k1y = h_hi(uk1);
        const float k2x = h_lo(uk2), k2y = h_hi(uk2);

        *(unsigned*)(Qf + obase + c1) = hpack2(q1x * sn0 - q2x * cs0, q1y * sn1 - q2y * cs1);
        *(unsigned*)(Qf + obase + c2) = hpack2(q2x * sn0 + q1x * cs0, q2y * sn1 + q1y * cs1);
        *(unsigned*)(Kfo + obase + c1) = hpack2((k1x * sn0 - k2x * cs0) * KS, (k1y * sn1 - k2y * cs1) * KS);
        *(unsigned*)(Kfo + obase + c2) = hpack2((k2x * sn0 + k1x * cs0) * KS, (k2y * sn1 + k1y * cs1) * KS);
    } else {
        const int vb = bx - B_ * S_;
        const int st = vb & 31;
        const int h  = (vb >> 5) & 15;
        const int b  = vb >> 9;
        const int s0 = st * 64;
#pragma unroll
        for (int it = 0; it < 2; ++it) {
            const int idx = it * 256 + t;
            const int row = idx >> 3;
            const int c8 = (idx & 7) * 8;
            const uint4 u = *(const uint4*)(qkv + ((size_t)(b * S_ + s0 + row)) * 3072 + 2048 + h * 64 + c8);
            T[row][c8+0] = u.x & 0xffffu; T[row][c8+1] = u.x >> 16;
            T[row][c8+2] = u.y & 0xffffu; T[row][c8+3] = u.y >> 16;
            T[row][c8+4] = u.z & 0xffffu; T[row][c8+5] = u.z >> 16;
            T[row][c8+6] = u.w & 0xffffu; T[row][c8+7] = u.w >> 16;
        }
        __syncthreads();
        const int d = t >> 2;
        const int scg = (t & 3) * 16;
        unsigned u[8];
#pragma unroll
        for (int ii = 0; ii < 8; ++ii)
            u[ii] = T[scg + 2*ii][d] | (T[scg + 2*ii + 1][d] << 16);
        unsigned short* dst = Vt + ((size_t)((b * H_ + h) * 64 + d)) * S_ + s0 + scg;
        *(uint4*)(dst)     = make_uint4(u[0], u[1], u[2], u[3]);
        *(uint4*)(dst + 8) = make_uint4(u[4], u[5], u[6], u[7]);
    }
}

// ---------------- MFMA flash attention, fp16, pipelined + XCD-swizzled --------
// S^T = K*Q^T (C col = query); exp2 softmax, no max-subtraction; l via ones-row
// MFMA on the SAME RTZ-packed P (exactly consistent). ctx written fp16.
__global__ __launch_bounds__(256)
void attn_mfma32(const unsigned short* __restrict__ Qf,
                 const unsigned short* __restrict__ Kfi,
                 const unsigned short* __restrict__ Vt,
                 unsigned short* __restrict__ Cf)
{
    __shared__ uint4 KF[512];   // 8 KB: K tile, A-frag order
    __shared__ uint4 VF[512];   // 8 KB: V^T tile, A-frag order

    const int t = threadIdx.x;
    const int i = blockIdx.x;                // [0, 1024)
    const int xcd = i & 7, j = i >> 3;
    const int bh = xcd * 8 + (j >> 4);
    const int qblk = j & 15;
    const int b = bh >> 4, h = bh & 15;

    const int w = t >> 6, l = t & 63;
    const int lq = l & 31, h5 = l >> 5;
    const int qrow = qblk * 128 + w * 32 + lq;

    half8 qf[4];
    const unsigned short* qp = Qf + ((size_t)(b * S_ + qrow)) * D_ + h * 64 + h5 * 8;
#pragma unroll
    for (int kc = 0; kc < 4; ++kc) qf[kc] = *(const half8*)(qp + kc * 16);

    floatx16 o0, o1, o2, z16;
#pragma unroll
    for (int r = 0; r < 16; ++r) { o0[r] = 0.f; o1[r] = 0.f; o2[r] = 0.f; z16[r] = 0.f; }

    union { unsigned u[4]; half8 s; } onesf;
    const unsigned ov = (lq == 0) ? 0x3C003C00u : 0u;   // fp16 1.0 pair
    onesf.u[0] = ov; onesf.u[1] = ov; onesf.u[2] = ov; onesf.u[3] = ov;

    const int sr = t >> 2, sc = t & 3;
    const unsigned short* gK0 = Kfi + ((size_t)(b * S_ + sr)) * D_ + h * 64 + sc * 16;
    const unsigned short* gV0 = Vt + ((size_t)((b * H_ + h) * 64 + sr)) * S_ + sc * 16;
    const int e0 = (sr >> 5) * 256 + sc * 64 + (sr & 31);

    const half8* pK = (const half8*)KF;
    const half8* pV = (const half8*)VF;

    uint4 ka  = *(const uint4*)(gK0);
    uint4 kb2 = *(const uint4*)(gK0 + 8);
    uint4 va  = *(const uint4*)(gV0);
    uint4 vb2 = *(const uint4*)(gV0 + 8);

    for (int kt = 0; kt < 32; ++kt) {
        __syncthreads();
        KF[e0] = ka; KF[e0 + 32] = kb2;
        VF[e0] = va; VF[e0 + 32] = vb2;
        __syncthreads();

        const int kn = (kt < 31) ? kt + 1 : kt;
        const unsigned short* gK = gK0 + (size_t)kn * 64 * D_;
        const unsigned short* gV = gV0 + (size_t)kn * 64;
        ka  = *(const uint4*)(gK);
        kb2 = *(const uint4*)(gK + 8);
        va  = *(const uint4*)(gV);
        vb2 = *(const uint4*)(gV + 8);

        floatx16 st0 = __builtin_amdgcn_mfma_f32_32x32x16_f16(pK[l],          qf[0], z16, 0, 0, 0);
        floatx16 st1 = __builtin_amdgcn_mfma_f32_32x32x16_f16(pK[4 * 64 + l], qf[0], z16, 0, 0, 0);
#pragma unroll
        for (int kc = 1; kc < 4; ++kc) {
            st0 = __builtin_amdgcn_mfma_f32_32x32x16_f16(pK[kc * 64 + l],       qf[kc], st0, 0, 0, 0);
            st1 = __builtin_amdgcn_mfma_f32_32x32x16_f16(pK[(4 + kc) * 64 + l], qf[kc], st1, 0, 0, 0);
        }

        unsigned pu0[8], pu1[8];
#pragma unroll
        for (int g = 0; g < 8; ++g) {
            pu0[g] = pkrtz(__builtin_amdgcn_exp2f(st0[2 * g]),
                           __builtin_amdgcn_exp2f(st0[2 * g + 1]));
            pu1[g] = pkrtz(__builtin_amdgcn_exp2f(st1[2 * g]),
                           __builtin_amdgcn_exp2f(st1[2 * g + 1]));
        }

#pragma unroll
        for (int kc = 0; kc < 4; ++kc) {
            const unsigned* pus = (kc >> 1) ? pu1 : pu0;
            const int g0 = (kc & 1) * 4;
            const unsigned own0 = h5 ? pus[g0 + 2] : pus[g0 + 0];
            const unsigned srv0 = h5 ? pus[g0 + 0] : pus[g0 + 2];
            const unsigned own1 = h5 ? pus[g0 + 3] : pus[g0 + 1];
            const unsigned srv1 = h5 ? pus[g0 + 1] : pus[g0 + 3];
            const unsigned par0 = (unsigned)__shfl_xor((int)srv0, 32, 64);
            const unsigned par1 = (unsigned)__shfl_xor((int)srv1, 32, 64);
            union { unsigned u[4]; half8 s; } pf;
            pf.u[0] = h5 ? par0 : own0;
            pf.u[1] = h5 ? par1 : own1;
            pf.u[2] = h5 ? own0 : par0;
            pf.u[3] = h5 ? own1 : par1;
            o0 = __builtin_amdgcn_mfma_f32_32x32x16_f16(pV[kc * 64 + l],       pf.s, o0, 0, 0, 0);
            o1 = __builtin_amdgcn_mfma_f32_32x32x16_f16(pV[(4 + kc) * 64 + l], pf.s, o1, 0, 0, 0);
            o2 = __builtin_amdgcn_mfma_f32_32x32x16_f16(onesf.s,               pf.s, o2, 0, 0, 0);
        }
    }

    const float lpart = o2[0];
    const float lothr = __shfl_xor(lpart, 32, 64);
    const float lsum = h5 ? lothr : lpart;
    const float inv = 1.0f / lsum;

    const size_t cbase = ((size_t)(b * S_ + qrow)) * D_ + h * 64;
#pragma unroll
    for (int rq = 0; rq < 4; ++rq) {
        const int d0 = rq * 8 + h5 * 4;
        const uint2 y0 = make_uint2(hpack2(o0[4*rq+0] * inv, o0[4*rq+1] * inv),
                                    hpack2(o0[4*rq+2] * inv, o0[4*rq+3] * inv));
        const uint2 y1 = make_uint2(hpack2(o1[4*rq+0] * inv, o1[4*rq+1] * inv),
                                    hpack2(o1[4*rq+2] * inv, o1[4*rq+3] * inv));
        *(uint2*)(Cf + cbase + d0)      = y0;
        *(uint2*)(Cf + cbase + 32 + d0) = y1;
    }
}

extern "C" void kernel_launch(void* const* d_in, const int* in_sizes, int n_in,
                              void* d_out, int out_size, void* d_ws, size_t ws_size,
                              hipStream_t stream) {
    (void)in_sizes; (void)n_in; (void)out_size; (void)ws_size;
    const float* X  = (const float*)d_in[0];
    const float* Wq = (const float*)d_in[1];
    const float* bq = (const float*)d_in[2];
    const float* Wk = (const float*)d_in[3];
    const float* bk = (const float*)d_in[4];
    const float* Wv = (const float*)d_in[5];
    const float* bv = (const float*)d_in[6];
    const float* Wo = (const float*)d_in[7];
    const float* bo = (const float*)d_in[8];
    float* out = (float*)d_out;

    char* ws = (char*)d_ws;
#define OFF(mb) (ws + ((size_t)(mb) << 20))
    unsigned short* Xf    = (unsigned short*)OFF(0);    // 16 MB (dead after QKV GEMM)
    unsigned short* qkv16 = (unsigned short*)OFF(16);   // 48 MB (dead after prep)
    unsigned short* Qf    = (unsigned short*)OFF(64);   // 16 MB
    unsigned short* Kfb   = (unsigned short*)OFF(80);   // 16 MB
    unsigned short* Vtb   = (unsigned short*)OFF(96);   // 16 MB
    unsigned short* Wqkvf = (unsigned short*)OFF(112);  // 6 MB
    unsigned short* Wof   = (unsigned short*)OFF(118);  // 2 MB
    float*          bqkv  = (float*)OFF(120);           // 12 KB
    unsigned short* Cf    = (unsigned short*)OFF(0);    // 16 MB overlay Xf
#undef OFF

    const int NX = B_ * S_ * D_;   // 8M
    conv_x<<<NX / 2048, 256, 0, stream>>>(X, Xf, NX);
    conv_weights<<<2049, 256, 0, stream>>>(Wq, Wk, Wv, Wo, bq, bk, bv,
                                           Wqkvf, Wof, bqkv);
    gemm_half<1><<<dim3(64, 24), 256, 0, stream>>>(Xf, Wqkvf, bqkv,
                                                   qkv16, B_*S_, 3 * D_, D_);
    prep_fused<<<B_*S_ + 2048, 256, 0, stream>>>(qkv16, Qf, Kfb, Vtb);
    attn_mfma32<<<1024, 256, 0, stream>>>(Qf, Kfb, Vtb, Cf);
    gemm_half<0><<<dim3(64, 8), 256, 0, stream>>>(Cf, Wof, bo, out, B_*S_, D_, D_);
}